// Round 1
// baseline (1123.198 us; speedup 1.0000x reference)
//
#include <hip/hip_runtime.h>

// Problem constants (B=4, S=4096 -> 16384 tokens; H=1024; M=H/2=512; E=8)
#define NTOK 16384
#define HDIM 1024
#define MDIM 512
#define NEXP 8
#define CHUNK 128
#define MAXCHUNK 136  // sum_e ceil(c_e/128) <= 16384/128 + 7 = 135; +1 slack

// ---------------------------------------------------------------------------
// GEMM1: h = relu(hs @ w1 + b1)   [NTOK x MDIM]
// 128x128 tile, BK=16, 256 threads, 8x8 micro (2x2 quadrants of 4x4)
// ---------------------------------------------------------------------------
__global__ __launch_bounds__(256) void gemm1_relu(
    const float* __restrict__ A,    // [NTOK][HDIM]
    const float* __restrict__ W,    // [HDIM][MDIM]
    const float* __restrict__ bias, // [MDIM]
    float* __restrict__ Hout)       // [NTOK][MDIM]
{
  __shared__ float As[16][132];  // transposed A tile, padded (132%4==0 -> b128 ok)
  __shared__ float Bs[16][128];

  const int tid = threadIdx.x;
  const int tx = tid & 15, ty = tid >> 4;
  const int row0 = blockIdx.y * 128;
  const int col0 = blockIdx.x * 128;

  float acc[8][8];
#pragma unroll
  for (int i = 0; i < 8; ++i)
#pragma unroll
    for (int j = 0; j < 8; ++j) acc[i][j] = 0.f;

  const int ar = tid >> 2;         // 0..63
  const int ak = (tid & 3) << 2;   // 0,4,8,12
  const int bk = tid >> 5;         // 0..7
  const int bc = (tid & 31) << 2;  // 0..124

  const float* pa0 = A + (size_t)(row0 + ar) * HDIM;
  const float* pa1 = A + (size_t)(row0 + ar + 64) * HDIM;

  for (int k0 = 0; k0 < HDIM; k0 += 16) {
    float4 a0 = *(const float4*)&pa0[k0 + ak];
    float4 a1 = *(const float4*)&pa1[k0 + ak];
    float4 b0 = *(const float4*)&W[(size_t)(k0 + bk) * MDIM + col0 + bc];
    float4 b1 = *(const float4*)&W[(size_t)(k0 + bk + 8) * MDIM + col0 + bc];

    As[ak + 0][ar] = a0.x; As[ak + 1][ar] = a0.y;
    As[ak + 2][ar] = a0.z; As[ak + 3][ar] = a0.w;
    As[ak + 0][ar + 64] = a1.x; As[ak + 1][ar + 64] = a1.y;
    As[ak + 2][ar + 64] = a1.z; As[ak + 3][ar + 64] = a1.w;
    *(float4*)&Bs[bk][bc] = b0;
    *(float4*)&Bs[bk + 8][bc] = b1;
    __syncthreads();

#pragma unroll
    for (int k = 0; k < 16; ++k) {
      float4 av0 = *(const float4*)&As[k][ty * 4];
      float4 av1 = *(const float4*)&As[k][64 + ty * 4];
      float4 bv0 = *(const float4*)&Bs[k][tx * 4];
      float4 bv1 = *(const float4*)&Bs[k][64 + tx * 4];
      float a[8] = {av0.x, av0.y, av0.z, av0.w, av1.x, av1.y, av1.z, av1.w};
      float b[8] = {bv0.x, bv0.y, bv0.z, bv0.w, bv1.x, bv1.y, bv1.z, bv1.w};
#pragma unroll
      for (int i = 0; i < 8; ++i)
#pragma unroll
        for (int j = 0; j < 8; ++j) acc[i][j] = fmaf(a[i], b[j], acc[i][j]);
    }
    __syncthreads();
  }

#pragma unroll
  for (int i = 0; i < 8; ++i) {
    const int r = row0 + ((i < 4) ? (ty * 4 + i) : (64 + ty * 4 + (i - 4)));
#pragma unroll
    for (int jq = 0; jq < 2; ++jq) {
      const int c = col0 + jq * 64 + tx * 4;
      float4 v;
      v.x = fmaxf(acc[i][jq * 4 + 0] + bias[c + 0], 0.f);
      v.y = fmaxf(acc[i][jq * 4 + 1] + bias[c + 1], 0.f);
      v.z = fmaxf(acc[i][jq * 4 + 2] + bias[c + 2], 0.f);
      v.w = fmaxf(acc[i][jq * 4 + 3] + bias[c + 3], 0.f);
      *(float4*)&Hout[(size_t)r * MDIM + c] = v;
    }
  }
}

// ---------------------------------------------------------------------------
// Routing scores + argmax + expert counts. One wave per token.
// ---------------------------------------------------------------------------
__global__ __launch_bounds__(256) void routing_scores(
    const float* __restrict__ Hq,   // [NTOK][MDIM]
    const float* __restrict__ w2,   // [MDIM][NEXP]
    const float* __restrict__ b2,   // [NEXP]
    int* __restrict__ top_idx,      // [NTOK]
    int* __restrict__ counts)       // [NEXP]
{
  const int warp = threadIdx.x >> 6;
  const int lane = threadIdx.x & 63;
  const int t = blockIdx.x * 4 + warp;
  const float* hrow = Hq + (size_t)t * MDIM;

  float s[8] = {0, 0, 0, 0, 0, 0, 0, 0};
  for (int k = lane; k < MDIM; k += 64) {
    float hv = hrow[k];
    float4 wa = *(const float4*)&w2[k * 8];
    float4 wb = *(const float4*)&w2[k * 8 + 4];
    s[0] += hv * wa.x; s[1] += hv * wa.y; s[2] += hv * wa.z; s[3] += hv * wa.w;
    s[4] += hv * wb.x; s[5] += hv * wb.y; s[6] += hv * wb.z; s[7] += hv * wb.w;
  }
#pragma unroll
  for (int off = 32; off > 0; off >>= 1)
#pragma unroll
    for (int e = 0; e < 8; ++e) s[e] += __shfl_xor(s[e], off, 64);

  if (lane == 0) {
    float best = s[0] + b2[0];
    int bi = 0;
#pragma unroll
    for (int e = 1; e < 8; ++e) {
      float v = s[e] + b2[e];
      if (v > best) { best = v; bi = e; }  // strict > keeps first max (jnp.argmax)
    }
    top_idx[t] = bi;
    atomicAdd(&counts[bi], 1);
  }
}

// ---------------------------------------------------------------------------
// Padded segment offsets (multiples of CHUNK) + cursor init. Single block.
// ---------------------------------------------------------------------------
__global__ void make_offsets(const int* __restrict__ counts,
                             int* __restrict__ pad_off,
                             int* __restrict__ cursor)
{
  if (threadIdx.x == 0) {
    int off = 0;
    for (int e = 0; e < NEXP; ++e) {
      pad_off[e] = off;
      off += ((counts[e] + CHUNK - 1) / CHUNK) * CHUNK;
    }
    pad_off[NEXP] = off;
  }
  if (threadIdx.x < NEXP) cursor[threadIdx.x] = 0;
}

// ---------------------------------------------------------------------------
// Scatter token ids into expert-sorted order (padded slots stay -1).
// ---------------------------------------------------------------------------
__global__ __launch_bounds__(256) void scatter_tokens(
    const int* __restrict__ top_idx,
    const int* __restrict__ pad_off,
    int* __restrict__ cursor,
    int* __restrict__ sorted)
{
  const int t = blockIdx.x * 256 + threadIdx.x;
  const int e = top_idx[t];
  const int r = atomicAdd(&cursor[e], 1);
  sorted[pad_off[e] + r] = t;
}

// ---------------------------------------------------------------------------
// Expert GEMM: out[t] = hs[t] @ W[e(t)] + b[e(t)] over expert-sorted chunks.
// Same 128x128/BK16 micro-kernel with gathered A rows and scattered C rows.
// ---------------------------------------------------------------------------
__global__ __launch_bounds__(256) void expert_gemm(
    const float* __restrict__ X,    // hs [NTOK][HDIM]
    const float* __restrict__ EW,   // [NEXP][HDIM][HDIM]
    const float* __restrict__ Eb,   // [NEXP][HDIM]
    const int* __restrict__ sorted, // [MAXCHUNK*CHUNK], -1 padded
    const int* __restrict__ top_idx,
    float* __restrict__ Out)        // [NTOK][HDIM]
{
  __shared__ float As[16][132];
  __shared__ float Bs[16][128];
  __shared__ int toks[CHUNK];

  const int tid = threadIdx.x;
  if (tid < CHUNK) toks[tid] = sorted[(size_t)blockIdx.y * CHUNK + tid];
  __syncthreads();
  if (toks[0] < 0) return;  // empty padded chunk (uniform across block)

  const int e = top_idx[toks[0]];  // chunks never straddle experts (aligned pads)
  const float* W = EW + (size_t)e * HDIM * HDIM;
  const int col0 = blockIdx.x * 128;

  const int tx = tid & 15, ty = tid >> 4;
  float acc[8][8];
#pragma unroll
  for (int i = 0; i < 8; ++i)
#pragma unroll
    for (int j = 0; j < 8; ++j) acc[i][j] = 0.f;

  const int ar = tid >> 2;
  const int ak = (tid & 3) << 2;
  const int bk = tid >> 5;
  const int bc = (tid & 31) << 2;

  const int tokA0 = toks[ar];
  const int tokA1 = toks[ar + 64];
  const float* pa0 = (tokA0 >= 0) ? X + (size_t)tokA0 * HDIM : X;
  const float* pa1 = (tokA1 >= 0) ? X + (size_t)tokA1 * HDIM : X;
  const float4 z4 = make_float4(0.f, 0.f, 0.f, 0.f);

  for (int k0 = 0; k0 < HDIM; k0 += 16) {
    float4 a0 = (tokA0 >= 0) ? *(const float4*)&pa0[k0 + ak] : z4;
    float4 a1 = (tokA1 >= 0) ? *(const float4*)&pa1[k0 + ak] : z4;
    float4 b0 = *(const float4*)&W[(size_t)(k0 + bk) * HDIM + col0 + bc];
    float4 b1 = *(const float4*)&W[(size_t)(k0 + bk + 8) * HDIM + col0 + bc];

    As[ak + 0][ar] = a0.x; As[ak + 1][ar] = a0.y;
    As[ak + 2][ar] = a0.z; As[ak + 3][ar] = a0.w;
    As[ak + 0][ar + 64] = a1.x; As[ak + 1][ar + 64] = a1.y;
    As[ak + 2][ar + 64] = a1.z; As[ak + 3][ar + 64] = a1.w;
    *(float4*)&Bs[bk][bc] = b0;
    *(float4*)&Bs[bk + 8][bc] = b1;
    __syncthreads();

#pragma unroll
    for (int k = 0; k < 16; ++k) {
      float4 av0 = *(const float4*)&As[k][ty * 4];
      float4 av1 = *(const float4*)&As[k][64 + ty * 4];
      float4 bv0 = *(const float4*)&Bs[k][tx * 4];
      float4 bv1 = *(const float4*)&Bs[k][64 + tx * 4];
      float a[8] = {av0.x, av0.y, av0.z, av0.w, av1.x, av1.y, av1.z, av1.w};
      float b[8] = {bv0.x, bv0.y, bv0.z, bv0.w, bv1.x, bv1.y, bv1.z, bv1.w};
#pragma unroll
      for (int i = 0; i < 8; ++i)
#pragma unroll
        for (int j = 0; j < 8; ++j) acc[i][j] = fmaf(a[i], b[j], acc[i][j]);
    }
    __syncthreads();
  }

  const float* be = Eb + (size_t)e * HDIM;
#pragma unroll
  for (int i = 0; i < 8; ++i) {
    const int rloc = (i < 4) ? (ty * 4 + i) : (64 + ty * 4 + (i - 4));
    const int tok = toks[rloc];
    if (tok < 0) continue;
#pragma unroll
    for (int jq = 0; jq < 2; ++jq) {
      const int c = col0 + jq * 64 + tx * 4;
      float4 v;
      v.x = acc[i][jq * 4 + 0] + be[c + 0];
      v.y = acc[i][jq * 4 + 1] + be[c + 1];
      v.z = acc[i][jq * 4 + 2] + be[c + 2];
      v.w = acc[i][jq * 4 + 3] + be[c + 3];
      *(float4*)&Out[(size_t)tok * HDIM + c] = v;
    }
  }
}

// ---------------------------------------------------------------------------
extern "C" void kernel_launch(void* const* d_in, const int* in_sizes, int n_in,
                              void* d_out, int out_size, void* d_ws, size_t ws_size,
                              hipStream_t stream) {
  (void)in_sizes; (void)n_in; (void)out_size; (void)ws_size;

  const float* hs = (const float*)d_in[0];
  const float* w1 = (const float*)d_in[1];
  const float* b1 = (const float*)d_in[2];
  const float* w2 = (const float*)d_in[3];
  const float* b2 = (const float*)d_in[4];
  const float* eW = (const float*)d_in[5];
  const float* eb = (const float*)d_in[6];
  float* out = (float*)d_out;

  // h intermediate [NTOK][MDIM] lives in d_out's first 33.5 MB: it is fully
  // consumed by routing_scores before expert_gemm overwrites all of d_out.
  float* h = (float*)d_out;

  char* ws = (char*)d_ws;
  int* top_idx = (int*)ws;                   // 65536 B
  int* counts  = (int*)(ws + 65536);         // 32 B
  int* pad_off = counts + NEXP;              // 36 B
  int* cursor  = pad_off + NEXP + 1;         // 32 B
  int* sorted  = (int*)(ws + 65536 + 256);   // 136*128*4 = 69632 B

  hipMemsetAsync(counts, 0, NEXP * sizeof(int), stream);
  hipMemsetAsync(sorted, 0xFF, MAXCHUNK * CHUNK * sizeof(int), stream);

  gemm1_relu<<<dim3(MDIM / 128, NTOK / 128), 256, 0, stream>>>(hs, w1, b1, h);
  routing_scores<<<NTOK / 4, 256, 0, stream>>>(h, w2, b2, top_idx, counts);
  make_offsets<<<1, 64, 0, stream>>>(counts, pad_off, cursor);
  scatter_tokens<<<NTOK / 256, 256, 0, stream>>>(top_idx, pad_off, cursor, sorted);
  expert_gemm<<<dim3(HDIM / 128, MAXCHUNK), 256, 0, stream>>>(hs, eW, eb, sorted, top_idx, out);
}

// Round 2
// 742.654 us; speedup vs baseline: 1.5124x; 1.5124x over previous
//
#include <hip/hip_runtime.h>

// Problem constants (B=4, S=4096 -> 16384 tokens; H=1024; M=H/2=512; E=8)
#define NTOK 16384
#define HDIM 1024
#define MDIM 512
#define NEXP 8
#define CHUNK 128
#define MAXCHUNK 136  // sum_e ceil(c_e/128) <= 16384/128 + 7 = 135; +1 slack

typedef __bf16 bf16x8 __attribute__((ext_vector_type(8)));
typedef float floatx4 __attribute__((ext_vector_type(4)));

// ---------------------------------------------------------------------------
// GEMM1: h = relu(hs @ w1 + b1)   [NTOK x MDIM]  (fp32 — feeds argmax routing,
// must match numpy fp32 closely; bf16 here would flip argmax for ~dozens of
// tokens -> absmax fail)
// ---------------------------------------------------------------------------
__global__ __launch_bounds__(256) void gemm1_relu(
    const float* __restrict__ A,    // [NTOK][HDIM]
    const float* __restrict__ W,    // [HDIM][MDIM]
    const float* __restrict__ bias, // [MDIM]
    float* __restrict__ Hout)       // [NTOK][MDIM]
{
  __shared__ float As[16][132];
  __shared__ float Bs[16][128];

  const int tid = threadIdx.x;
  const int tx = tid & 15, ty = tid >> 4;
  const int row0 = blockIdx.y * 128;
  const int col0 = blockIdx.x * 128;

  float acc[8][8];
#pragma unroll
  for (int i = 0; i < 8; ++i)
#pragma unroll
    for (int j = 0; j < 8; ++j) acc[i][j] = 0.f;

  const int ar = tid >> 2;
  const int ak = (tid & 3) << 2;
  const int bk = tid >> 5;
  const int bc = (tid & 31) << 2;

  const float* pa0 = A + (size_t)(row0 + ar) * HDIM;
  const float* pa1 = A + (size_t)(row0 + ar + 64) * HDIM;

  for (int k0 = 0; k0 < HDIM; k0 += 16) {
    float4 a0 = *(const float4*)&pa0[k0 + ak];
    float4 a1 = *(const float4*)&pa1[k0 + ak];
    float4 b0 = *(const float4*)&W[(size_t)(k0 + bk) * MDIM + col0 + bc];
    float4 b1 = *(const float4*)&W[(size_t)(k0 + bk + 8) * MDIM + col0 + bc];

    As[ak + 0][ar] = a0.x; As[ak + 1][ar] = a0.y;
    As[ak + 2][ar] = a0.z; As[ak + 3][ar] = a0.w;
    As[ak + 0][ar + 64] = a1.x; As[ak + 1][ar + 64] = a1.y;
    As[ak + 2][ar + 64] = a1.z; As[ak + 3][ar + 64] = a1.w;
    *(float4*)&Bs[bk][bc] = b0;
    *(float4*)&Bs[bk + 8][bc] = b1;
    __syncthreads();

#pragma unroll
    for (int k = 0; k < 16; ++k) {
      float4 av0 = *(const float4*)&As[k][ty * 4];
      float4 av1 = *(const float4*)&As[k][64 + ty * 4];
      float4 bv0 = *(const float4*)&Bs[k][tx * 4];
      float4 bv1 = *(const float4*)&Bs[k][64 + tx * 4];
      float a[8] = {av0.x, av0.y, av0.z, av0.w, av1.x, av1.y, av1.z, av1.w};
      float b[8] = {bv0.x, bv0.y, bv0.z, bv0.w, bv1.x, bv1.y, bv1.z, bv1.w};
#pragma unroll
      for (int i = 0; i < 8; ++i)
#pragma unroll
        for (int j = 0; j < 8; ++j) acc[i][j] = fmaf(a[i], b[j], acc[i][j]);
    }
    __syncthreads();
  }

#pragma unroll
  for (int i = 0; i < 8; ++i) {
    const int r = row0 + ((i < 4) ? (ty * 4 + i) : (64 + ty * 4 + (i - 4)));
#pragma unroll
    for (int jq = 0; jq < 2; ++jq) {
      const int c = col0 + jq * 64 + tx * 4;
      float4 v;
      v.x = fmaxf(acc[i][jq * 4 + 0] + bias[c + 0], 0.f);
      v.y = fmaxf(acc[i][jq * 4 + 1] + bias[c + 1], 0.f);
      v.z = fmaxf(acc[i][jq * 4 + 2] + bias[c + 2], 0.f);
      v.w = fmaxf(acc[i][jq * 4 + 3] + bias[c + 3], 0.f);
      *(float4*)&Hout[(size_t)r * MDIM + c] = v;
    }
  }
}

// ---------------------------------------------------------------------------
// Routing scores + argmax + expert counts. One wave per token. (fp32)
// ---------------------------------------------------------------------------
__global__ __launch_bounds__(256) void routing_scores(
    const float* __restrict__ Hq,   // [NTOK][MDIM]
    const float* __restrict__ w2,   // [MDIM][NEXP]
    const float* __restrict__ b2,   // [NEXP]
    int* __restrict__ top_idx,      // [NTOK]
    int* __restrict__ counts)       // [NEXP]
{
  const int warp = threadIdx.x >> 6;
  const int lane = threadIdx.x & 63;
  const int t = blockIdx.x * 4 + warp;
  const float* hrow = Hq + (size_t)t * MDIM;

  float s[8] = {0, 0, 0, 0, 0, 0, 0, 0};
  for (int k = lane; k < MDIM; k += 64) {
    float hv = hrow[k];
    float4 wa = *(const float4*)&w2[k * 8];
    float4 wb = *(const float4*)&w2[k * 8 + 4];
    s[0] += hv * wa.x; s[1] += hv * wa.y; s[2] += hv * wa.z; s[3] += hv * wa.w;
    s[4] += hv * wb.x; s[5] += hv * wb.y; s[6] += hv * wb.z; s[7] += hv * wb.w;
  }
#pragma unroll
  for (int off = 32; off > 0; off >>= 1)
#pragma unroll
    for (int e = 0; e < 8; ++e) s[e] += __shfl_xor(s[e], off, 64);

  if (lane == 0) {
    float best = s[0] + b2[0];
    int bi = 0;
#pragma unroll
    for (int e = 1; e < 8; ++e) {
      float v = s[e] + b2[e];
      if (v > best) { best = v; bi = e; }  // strict > keeps first max (jnp.argmax)
    }
    top_idx[t] = bi;
    atomicAdd(&counts[bi], 1);
  }
}

// ---------------------------------------------------------------------------
__global__ void make_offsets(const int* __restrict__ counts,
                             int* __restrict__ pad_off,
                             int* __restrict__ cursor)
{
  if (threadIdx.x == 0) {
    int off = 0;
    for (int e = 0; e < NEXP; ++e) {
      pad_off[e] = off;
      off += ((counts[e] + CHUNK - 1) / CHUNK) * CHUNK;
    }
    pad_off[NEXP] = off;
  }
  if (threadIdx.x < NEXP) cursor[threadIdx.x] = 0;
}

__global__ __launch_bounds__(256) void scatter_tokens(
    const int* __restrict__ top_idx,
    const int* __restrict__ pad_off,
    int* __restrict__ cursor,
    int* __restrict__ sorted)
{
  const int t = blockIdx.x * 256 + threadIdx.x;
  const int e = top_idx[t];
  const int r = atomicAdd(&cursor[e], 1);
  sorted[pad_off[e] + r] = t;
}

// ---------------------------------------------------------------------------
// Expert GEMM, bf16 MFMA: out[t] = hs[t] @ W[e(t)] + b[e(t)].
// 128x128 tile, BK=32, 4 waves x (64x64 via 4x4 mfma_f32_16x16x32_bf16).
// fp32 -> bf16 cast happens in-register during LDS staging (fp32 accum).
// LDS rows padded to 40 bf16 (20 dwords): every b128 read/write lands on the
// uniform 8-phase floor (conflict-free).
// ---------------------------------------------------------------------------
#define ASTRIDE 40

__global__ __launch_bounds__(256) void expert_gemm_bf16(
    const float* __restrict__ X,    // hs [NTOK][HDIM]
    const float* __restrict__ EW,   // [NEXP][HDIM][HDIM]
    const float* __restrict__ Eb,   // [NEXP][HDIM]
    const int* __restrict__ sorted, // [MAXCHUNK*CHUNK], -1 padded
    const int* __restrict__ top_idx,
    float* __restrict__ Out)        // [NTOK][HDIM]
{
  __shared__ __bf16 As[128 * ASTRIDE];
  __shared__ __bf16 Bs[128 * ASTRIDE];
  __shared__ int toks[CHUNK];

  const int tid = threadIdx.x;
  if (tid < CHUNK) toks[tid] = sorted[(size_t)blockIdx.y * CHUNK + tid];
  __syncthreads();
  if (toks[0] < 0) return;  // empty padded chunk (uniform across block)

  const int e = top_idx[toks[0]];
  const float* W = EW + (size_t)e * HDIM * HDIM;
  const int col0 = blockIdx.x * 128;

  // A staging: thread -> (row, k-half)
  const int arow = tid >> 1;          // 0..127
  const int akh = (tid & 1) * 16;     // 0 | 16
  const int tokA = toks[arow];
  const float* pA = (tokA >= 0) ? X + (size_t)tokA * HDIM + akh : X;

  // B staging: thread -> (col, k-half); dword loads coalesce across 64 cols
  const int bcol = tid & 127;
  const int bkh = (tid >> 7) * 16;
  const float* pB = W + (size_t)bkh * HDIM + col0 + bcol;

  // wave tile
  const int wave = tid >> 6;
  const int lane = tid & 63;
  const int wr = (wave >> 1) * 64;
  const int wc = (wave & 1) * 64;
  const int lrow = lane & 15;
  const int quad = lane >> 4;

  floatx4 acc[4][4];
#pragma unroll
  for (int i = 0; i < 4; ++i)
#pragma unroll
    for (int j = 0; j < 4; ++j) acc[i][j] = (floatx4){0.f, 0.f, 0.f, 0.f};

  for (int k0 = 0; k0 < HDIM; k0 += 32) {
    // ---- stage A (gathered token rows) ----
    float4 av0, av1, av2, av3;
    if (tokA >= 0) {
      av0 = *(const float4*)&pA[k0 + 0];
      av1 = *(const float4*)&pA[k0 + 4];
      av2 = *(const float4*)&pA[k0 + 8];
      av3 = *(const float4*)&pA[k0 + 12];
    } else {
      av0 = av1 = av2 = av3 = make_float4(0.f, 0.f, 0.f, 0.f);
    }
    // ---- stage B (transpose W[k][col] -> Bs[col][k]) ----
    float bv[16];
    {
      const float* p = pB + (size_t)k0 * HDIM;
#pragma unroll
      for (int j = 0; j < 16; ++j) bv[j] = p[(size_t)j * HDIM];
    }

    bf16x8 pa0, pa1, pb0, pb1;
    pa0[0] = (__bf16)av0.x; pa0[1] = (__bf16)av0.y; pa0[2] = (__bf16)av0.z; pa0[3] = (__bf16)av0.w;
    pa0[4] = (__bf16)av1.x; pa0[5] = (__bf16)av1.y; pa0[6] = (__bf16)av1.z; pa0[7] = (__bf16)av1.w;
    pa1[0] = (__bf16)av2.x; pa1[1] = (__bf16)av2.y; pa1[2] = (__bf16)av2.z; pa1[3] = (__bf16)av2.w;
    pa1[4] = (__bf16)av3.x; pa1[5] = (__bf16)av3.y; pa1[6] = (__bf16)av3.z; pa1[7] = (__bf16)av3.w;
#pragma unroll
    for (int j = 0; j < 8; ++j) pb0[j] = (__bf16)bv[j];
#pragma unroll
    for (int j = 0; j < 8; ++j) pb1[j] = (__bf16)bv[8 + j];

    *(bf16x8*)&As[arow * ASTRIDE + akh + 0] = pa0;
    *(bf16x8*)&As[arow * ASTRIDE + akh + 8] = pa1;
    *(bf16x8*)&Bs[bcol * ASTRIDE + bkh + 0] = pb0;
    *(bf16x8*)&Bs[bcol * ASTRIDE + bkh + 8] = pb1;
    __syncthreads();

    // ---- fragments + MFMA ----
    bf16x8 a[4], b[4];
#pragma unroll
    for (int i = 0; i < 4; ++i)
      a[i] = *(const bf16x8*)&As[(wr + i * 16 + lrow) * ASTRIDE + quad * 8];
#pragma unroll
    for (int j = 0; j < 4; ++j)
      b[j] = *(const bf16x8*)&Bs[(wc + j * 16 + lrow) * ASTRIDE + quad * 8];

#pragma unroll
    for (int i = 0; i < 4; ++i)
#pragma unroll
      for (int j = 0; j < 4; ++j)
        acc[i][j] = __builtin_amdgcn_mfma_f32_16x16x32_bf16(a[i], b[j], acc[i][j], 0, 0, 0);
    __syncthreads();
  }

  // ---- epilogue: bias + scatter store ----
  const float* be = Eb + (size_t)e * HDIM + col0;
#pragma unroll
  for (int i = 0; i < 4; ++i) {
#pragma unroll
    for (int r = 0; r < 4; ++r) {
      const int row = wr + i * 16 + quad * 4 + r;
      const int tok = toks[row];
      if (tok < 0) continue;
      float* po = Out + (size_t)tok * HDIM + col0;
#pragma unroll
      for (int j = 0; j < 4; ++j) {
        const int col = wc + j * 16 + lrow;
        po[col] = acc[i][j][r] + be[col];
      }
    }
  }
}

// ---------------------------------------------------------------------------
extern "C" void kernel_launch(void* const* d_in, const int* in_sizes, int n_in,
                              void* d_out, int out_size, void* d_ws, size_t ws_size,
                              hipStream_t stream) {
  (void)in_sizes; (void)n_in; (void)out_size; (void)ws_size;

  const float* hs = (const float*)d_in[0];
  const float* w1 = (const float*)d_in[1];
  const float* b1 = (const float*)d_in[2];
  const float* w2 = (const float*)d_in[3];
  const float* b2 = (const float*)d_in[4];
  const float* eW = (const float*)d_in[5];
  const float* eb = (const float*)d_in[6];
  float* out = (float*)d_out;

  // h intermediate lives in d_out: fully consumed by routing_scores before
  // expert_gemm overwrites d_out.
  float* h = (float*)d_out;

  char* ws = (char*)d_ws;
  int* top_idx = (int*)ws;                   // 65536 B
  int* counts  = (int*)(ws + 65536);
  int* pad_off = counts + NEXP;
  int* cursor  = pad_off + NEXP + 1;
  int* sorted  = (int*)(ws + 65536 + 256);   // 136*128*4 B

  hipMemsetAsync(counts, 0, NEXP * sizeof(int), stream);
  hipMemsetAsync(sorted, 0xFF, MAXCHUNK * CHUNK * sizeof(int), stream);

  gemm1_relu<<<dim3(MDIM / 128, NTOK / 128), 256, 0, stream>>>(hs, w1, b1, h);
  routing_scores<<<NTOK / 4, 256, 0, stream>>>(h, w2, b2, top_idx, counts);
  make_offsets<<<1, 64, 0, stream>>>(counts, pad_off, cursor);
  scatter_tokens<<<NTOK / 256, 256, 0, stream>>>(top_idx, pad_off, cursor, sorted);
  expert_gemm_bf16<<<dim3(HDIM / 128, MAXCHUNK), 256, 0, stream>>>(hs, eW, eb, sorted, top_idx, out);
}

// Round 3
// 531.125 us; speedup vs baseline: 2.1148x; 1.3983x over previous
//
#include <hip/hip_runtime.h>

// Problem constants (B=4, S=4096 -> 16384 tokens; H=1024; M=H/2=512; E=8)
#define NTOK 16384
#define HDIM 1024
#define MDIM 512
#define NEXP 8
#define CHUNK 128
#define MAXCHUNK 136   // sum_e ceil(c_e/128) <= 16384/128 + 7 = 135; +1 slack
#define RCAP 4096      // capacity of the "risky token" fixup list (expect ~800)
#define DELTA 0.02f    // top2-gap threshold = ~12 sigma of bf16 score noise

typedef __bf16 bf16x8 __attribute__((ext_vector_type(8)));
typedef float floatx4 __attribute__((ext_vector_type(4)));

// ---------------------------------------------------------------------------
// GEMM1 (bf16 MFMA): h = relu(hs @ w1 + b1). h only feeds argmax routing;
// bf16 noise (~1e-3 in scores) is handled by the delta-guarded fp32 fixup.
// 128x128 tile, BK=32, 4 waves x 4x4 mfma_f32_16x16x32_bf16. LDS rows padded
// to 40 bf16 -> all b128 accesses conflict-free.
// ---------------------------------------------------------------------------
#define ASTRIDE 40

__global__ __launch_bounds__(256) void gemm1_relu_bf16(
    const float* __restrict__ A,    // hs [NTOK][HDIM]
    const float* __restrict__ W,    // w1 [HDIM][MDIM]
    const float* __restrict__ bias, // b1 [MDIM]
    float* __restrict__ Hout)       // [NTOK][MDIM]
{
  __shared__ __bf16 As[128 * ASTRIDE];
  __shared__ __bf16 Bs[128 * ASTRIDE];

  const int tid = threadIdx.x;
  const int row0 = blockIdx.y * 128;
  const int col0 = blockIdx.x * 128;

  const int arow = tid >> 1;
  const int akh = (tid & 1) * 16;
  const float* pA = A + (size_t)(row0 + arow) * HDIM + akh;

  const int bcol = tid & 127;
  const int bkh = (tid >> 7) * 16;
  const float* pB = W + (size_t)bkh * MDIM + col0 + bcol;

  const int wave = tid >> 6;
  const int lane = tid & 63;
  const int wr = (wave >> 1) * 64;
  const int wc = (wave & 1) * 64;
  const int lrow = lane & 15;
  const int quad = lane >> 4;

  floatx4 acc[4][4];
#pragma unroll
  for (int i = 0; i < 4; ++i)
#pragma unroll
    for (int j = 0; j < 4; ++j) acc[i][j] = (floatx4){0.f, 0.f, 0.f, 0.f};

  for (int k0 = 0; k0 < HDIM; k0 += 32) {
    float4 av0 = *(const float4*)&pA[k0 + 0];
    float4 av1 = *(const float4*)&pA[k0 + 4];
    float4 av2 = *(const float4*)&pA[k0 + 8];
    float4 av3 = *(const float4*)&pA[k0 + 12];
    float bv[16];
    {
      const float* p = pB + (size_t)k0 * MDIM;
#pragma unroll
      for (int j = 0; j < 16; ++j) bv[j] = p[(size_t)j * MDIM];
    }

    bf16x8 pa0, pa1, pb0, pb1;
    pa0[0] = (__bf16)av0.x; pa0[1] = (__bf16)av0.y; pa0[2] = (__bf16)av0.z; pa0[3] = (__bf16)av0.w;
    pa0[4] = (__bf16)av1.x; pa0[5] = (__bf16)av1.y; pa0[6] = (__bf16)av1.z; pa0[7] = (__bf16)av1.w;
    pa1[0] = (__bf16)av2.x; pa1[1] = (__bf16)av2.y; pa1[2] = (__bf16)av2.z; pa1[3] = (__bf16)av2.w;
    pa1[4] = (__bf16)av3.x; pa1[5] = (__bf16)av3.y; pa1[6] = (__bf16)av3.z; pa1[7] = (__bf16)av3.w;
#pragma unroll
    for (int j = 0; j < 8; ++j) pb0[j] = (__bf16)bv[j];
#pragma unroll
    for (int j = 0; j < 8; ++j) pb1[j] = (__bf16)bv[8 + j];

    *(bf16x8*)&As[arow * ASTRIDE + akh + 0] = pa0;
    *(bf16x8*)&As[arow * ASTRIDE + akh + 8] = pa1;
    *(bf16x8*)&Bs[bcol * ASTRIDE + bkh + 0] = pb0;
    *(bf16x8*)&Bs[bcol * ASTRIDE + bkh + 8] = pb1;
    __syncthreads();

    bf16x8 a[4], b[4];
#pragma unroll
    for (int i = 0; i < 4; ++i)
      a[i] = *(const bf16x8*)&As[(wr + i * 16 + lrow) * ASTRIDE + quad * 8];
#pragma unroll
    for (int j = 0; j < 4; ++j)
      b[j] = *(const bf16x8*)&Bs[(wc + j * 16 + lrow) * ASTRIDE + quad * 8];

#pragma unroll
    for (int i = 0; i < 4; ++i)
#pragma unroll
      for (int j = 0; j < 4; ++j)
        acc[i][j] = __builtin_amdgcn_mfma_f32_16x16x32_bf16(a[i], b[j], acc[i][j], 0, 0, 0);
    __syncthreads();
  }

#pragma unroll
  for (int i = 0; i < 4; ++i)
#pragma unroll
    for (int r = 0; r < 4; ++r) {
      const int row = row0 + wr + i * 16 + quad * 4 + r;
#pragma unroll
      for (int j = 0; j < 4; ++j) {
        const int col = col0 + wc + j * 16 + lrow;
        Hout[(size_t)row * MDIM + col] = fmaxf(acc[i][j][r] + bias[col], 0.f);
      }
    }
}

// ---------------------------------------------------------------------------
// Routing: fp32 scores from (approx) h, argmax -> top_idx. Tokens with
// top2 gap < DELTA are appended to the risky list (LDS-aggregated, one
// global atomic per block). NO count atomics here.
// ---------------------------------------------------------------------------
__global__ __launch_bounds__(256) void routing_flag(
    const float* __restrict__ Hq,   // [NTOK][MDIM]
    const float* __restrict__ w2,   // [MDIM][NEXP]
    const float* __restrict__ b2,   // [NEXP]
    int* __restrict__ top_idx,      // [NTOK]
    int* __restrict__ risky_n,
    int* __restrict__ risky)        // [RCAP]
{
  __shared__ int rbuf[4];
  __shared__ int rcnt;
  if (threadIdx.x == 0) rcnt = 0;
  __syncthreads();

  const int warp = threadIdx.x >> 6;
  const int lane = threadIdx.x & 63;
  const int t = blockIdx.x * 4 + warp;
  const float* hrow = Hq + (size_t)t * MDIM;

  float s[8] = {0, 0, 0, 0, 0, 0, 0, 0};
  for (int k = lane; k < MDIM; k += 64) {
    float hv = hrow[k];
    float4 wa = *(const float4*)&w2[k * 8];
    float4 wb = *(const float4*)&w2[k * 8 + 4];
    s[0] += hv * wa.x; s[1] += hv * wa.y; s[2] += hv * wa.z; s[3] += hv * wa.w;
    s[4] += hv * wb.x; s[5] += hv * wb.y; s[6] += hv * wb.z; s[7] += hv * wb.w;
  }
#pragma unroll
  for (int off = 32; off > 0; off >>= 1)
#pragma unroll
    for (int e = 0; e < 8; ++e) s[e] += __shfl_xor(s[e], off, 64);

  if (lane == 0) {
    float best = s[0] + b2[0], second = -1e30f;
    int bi = 0;
#pragma unroll
    for (int e = 1; e < 8; ++e) {
      float v = s[e] + b2[e];
      if (v > best) { second = best; best = v; bi = e; }
      else if (v > second) second = v;
    }
    top_idx[t] = bi;
    if (best - second < DELTA) {
      int slot = atomicAdd(&rcnt, 1);  // LDS atomic
      rbuf[slot] = t;
    }
  }
  __syncthreads();
  if (threadIdx.x == 0 && rcnt > 0) {
    int base = atomicAdd(risky_n, rcnt);
    for (int i = 0; i < rcnt; ++i)
      if (base + i < RCAP) risky[base + i] = rbuf[i];
  }
}

// ---------------------------------------------------------------------------
// Exact fp32 recompute of h rows for risky tokens (gathered 128x128 GEMM).
// ---------------------------------------------------------------------------
__global__ __launch_bounds__(256) void gemm1_fix(
    const float* __restrict__ A,    // hs [NTOK][HDIM]
    const float* __restrict__ W,    // w1 [HDIM][MDIM]
    const float* __restrict__ bias, // b1
    const int* __restrict__ risky,  // [RCAP], -1 padded
    float* __restrict__ Hout)       // [NTOK][MDIM]
{
  __shared__ float As[16][132];
  __shared__ float Bs[16][128];
  __shared__ int toks[128];

  const int tid = threadIdx.x;
  if (tid < 128) toks[tid] = risky[blockIdx.y * 128 + tid];
  __syncthreads();
  if (toks[0] < 0) return;  // compact list -> empty chunk is uniform

  const int col0 = blockIdx.x * 128;
  const int tx = tid & 15, ty = tid >> 4;

  float acc[8][8];
#pragma unroll
  for (int i = 0; i < 8; ++i)
#pragma unroll
    for (int j = 0; j < 8; ++j) acc[i][j] = 0.f;

  const int ar = tid >> 2;
  const int ak = (tid & 3) << 2;
  const int bk = tid >> 5;
  const int bc = (tid & 31) << 2;

  const int tok0 = toks[ar];
  const int tok1 = toks[ar + 64];
  const float* pa0 = (tok0 >= 0) ? A + (size_t)tok0 * HDIM : A;
  const float* pa1 = (tok1 >= 0) ? A + (size_t)tok1 * HDIM : A;
  const float4 z4 = make_float4(0.f, 0.f, 0.f, 0.f);

  for (int k0 = 0; k0 < HDIM; k0 += 16) {
    float4 a0 = (tok0 >= 0) ? *(const float4*)&pa0[k0 + ak] : z4;
    float4 a1 = (tok1 >= 0) ? *(const float4*)&pa1[k0 + ak] : z4;
    float4 b0 = *(const float4*)&W[(size_t)(k0 + bk) * MDIM + col0 + bc];
    float4 b1 = *(const float4*)&W[(size_t)(k0 + bk + 8) * MDIM + col0 + bc];

    As[ak + 0][ar] = a0.x; As[ak + 1][ar] = a0.y;
    As[ak + 2][ar] = a0.z; As[ak + 3][ar] = a0.w;
    As[ak + 0][ar + 64] = a1.x; As[ak + 1][ar + 64] = a1.y;
    As[ak + 2][ar + 64] = a1.z; As[ak + 3][ar + 64] = a1.w;
    *(float4*)&Bs[bk][bc] = b0;
    *(float4*)&Bs[bk + 8][bc] = b1;
    __syncthreads();

#pragma unroll
    for (int k = 0; k < 16; ++k) {
      float4 av0 = *(const float4*)&As[k][ty * 4];
      float4 av1 = *(const float4*)&As[k][64 + ty * 4];
      float4 bv0 = *(const float4*)&Bs[k][tx * 4];
      float4 bv1 = *(const float4*)&Bs[k][64 + tx * 4];
      float a[8] = {av0.x, av0.y, av0.z, av0.w, av1.x, av1.y, av1.z, av1.w};
      float b[8] = {bv0.x, bv0.y, bv0.z, bv0.w, bv1.x, bv1.y, bv1.z, bv1.w};
#pragma unroll
      for (int i = 0; i < 8; ++i)
#pragma unroll
        for (int j = 0; j < 8; ++j) acc[i][j] = fmaf(a[i], b[j], acc[i][j]);
    }
    __syncthreads();
  }

#pragma unroll
  for (int i = 0; i < 8; ++i) {
    const int rloc = (i < 4) ? (ty * 4 + i) : (64 + ty * 4 + (i - 4));
    const int tok = toks[rloc];
    if (tok < 0) continue;
#pragma unroll
    for (int jq = 0; jq < 2; ++jq) {
      const int c = col0 + jq * 64 + tx * 4;
      float4 v;
      v.x = fmaxf(acc[i][jq * 4 + 0] + bias[c + 0], 0.f);
      v.y = fmaxf(acc[i][jq * 4 + 1] + bias[c + 1], 0.f);
      v.z = fmaxf(acc[i][jq * 4 + 2] + bias[c + 2], 0.f);
      v.w = fmaxf(acc[i][jq * 4 + 3] + bias[c + 3], 0.f);
      *(float4*)&Hout[(size_t)tok * MDIM + c] = v;
    }
  }
}

// ---------------------------------------------------------------------------
// Re-score risky tokens from exact h (8 lanes per token), overwrite top_idx.
// ---------------------------------------------------------------------------
__global__ __launch_bounds__(256) void rescore_fix(
    const float* __restrict__ Hq,
    const float* __restrict__ w2,
    const float* __restrict__ b2,
    const int* __restrict__ risky,  // [RCAP]
    int* __restrict__ top_idx)
{
  const int idx = blockIdx.x * 32 + (threadIdx.x >> 3);
  const int l8 = threadIdx.x & 7;
  const int t = risky[idx];

  float s[8] = {0, 0, 0, 0, 0, 0, 0, 0};
  if (t >= 0) {
    const float* hrow = Hq + (size_t)t * MDIM;
    for (int k = l8; k < MDIM; k += 8) {
      float hv = hrow[k];
      float4 wa = *(const float4*)&w2[k * 8];
      float4 wb = *(const float4*)&w2[k * 8 + 4];
      s[0] += hv * wa.x; s[1] += hv * wa.y; s[2] += hv * wa.z; s[3] += hv * wa.w;
      s[4] += hv * wb.x; s[5] += hv * wb.y; s[6] += hv * wb.z; s[7] += hv * wb.w;
    }
  }
#pragma unroll
  for (int off = 4; off > 0; off >>= 1)
#pragma unroll
    for (int e = 0; e < 8; ++e) s[e] += __shfl_xor(s[e], off, 64);

  if (l8 == 0 && t >= 0) {
    float best = s[0] + b2[0];
    int bi = 0;
#pragma unroll
    for (int e = 1; e < 8; ++e) {
      float v = s[e] + b2[e];
      if (v > best) { best = v; bi = e; }
    }
    top_idx[t] = bi;
  }
}

// ---------------------------------------------------------------------------
// Count tokens per expert — LDS-aggregated (8 global atomics / 256 tokens).
// ---------------------------------------------------------------------------
__global__ __launch_bounds__(256) void count_tokens(
    const int* __restrict__ top_idx, int* __restrict__ counts)
{
  __shared__ int lc[NEXP];
  if (threadIdx.x < NEXP) lc[threadIdx.x] = 0;
  __syncthreads();
  const int t = blockIdx.x * 256 + threadIdx.x;
  atomicAdd(&lc[top_idx[t]], 1);
  __syncthreads();
  if (threadIdx.x < NEXP) atomicAdd(&counts[threadIdx.x], lc[threadIdx.x]);
}

__global__ void make_offsets(const int* __restrict__ counts,
                             int* __restrict__ pad_off)
{
  if (threadIdx.x == 0) {
    int off = 0;
    for (int e = 0; e < NEXP; ++e) {
      pad_off[e] = off;
      off += ((counts[e] + CHUNK - 1) / CHUNK) * CHUNK;
    }
    pad_off[NEXP] = off;
  }
}

// ---------------------------------------------------------------------------
// Scatter with LDS rank + per-block range claim (8 global atomics / block).
// Order within an expert segment is irrelevant.
// ---------------------------------------------------------------------------
__global__ __launch_bounds__(256) void scatter_tokens(
    const int* __restrict__ top_idx,
    const int* __restrict__ pad_off,
    int* __restrict__ cursor,
    int* __restrict__ sorted)
{
  __shared__ int lc[NEXP];
  __shared__ int lbase[NEXP];
  if (threadIdx.x < NEXP) lc[threadIdx.x] = 0;
  __syncthreads();
  const int t = blockIdx.x * 256 + threadIdx.x;
  const int e = top_idx[t];
  const int r = atomicAdd(&lc[e], 1);
  __syncthreads();
  if (threadIdx.x < NEXP)
    lbase[threadIdx.x] = atomicAdd(&cursor[threadIdx.x], lc[threadIdx.x]);
  __syncthreads();
  sorted[pad_off[e] + lbase[e] + r] = t;
}

// ---------------------------------------------------------------------------
// Expert GEMM, bf16 MFMA (unchanged from R2).
// ---------------------------------------------------------------------------
__global__ __launch_bounds__(256) void expert_gemm_bf16(
    const float* __restrict__ X,
    const float* __restrict__ EW,
    const float* __restrict__ Eb,
    const int* __restrict__ sorted,
    const int* __restrict__ top_idx,
    float* __restrict__ Out)
{
  __shared__ __bf16 As[128 * ASTRIDE];
  __shared__ __bf16 Bs[128 * ASTRIDE];
  __shared__ int toks[CHUNK];

  const int tid = threadIdx.x;
  if (tid < CHUNK) toks[tid] = sorted[(size_t)blockIdx.y * CHUNK + tid];
  __syncthreads();
  if (toks[0] < 0) return;

  const int e = top_idx[toks[0]];
  const float* W = EW + (size_t)e * HDIM * HDIM;
  const int col0 = blockIdx.x * 128;

  const int arow = tid >> 1;
  const int akh = (tid & 1) * 16;
  const int tokA = toks[arow];
  const float* pA = (tokA >= 0) ? X + (size_t)tokA * HDIM + akh : X;

  const int bcol = tid & 127;
  const int bkh = (tid >> 7) * 16;
  const float* pB = W + (size_t)bkh * HDIM + col0 + bcol;

  const int wave = tid >> 6;
  const int lane = tid & 63;
  const int wr = (wave >> 1) * 64;
  const int wc = (wave & 1) * 64;
  const int lrow = lane & 15;
  const int quad = lane >> 4;

  floatx4 acc[4][4];
#pragma unroll
  for (int i = 0; i < 4; ++i)
#pragma unroll
    for (int j = 0; j < 4; ++j) acc[i][j] = (floatx4){0.f, 0.f, 0.f, 0.f};

  for (int k0 = 0; k0 < HDIM; k0 += 32) {
    float4 av0, av1, av2, av3;
    if (tokA >= 0) {
      av0 = *(const float4*)&pA[k0 + 0];
      av1 = *(const float4*)&pA[k0 + 4];
      av2 = *(const float4*)&pA[k0 + 8];
      av3 = *(const float4*)&pA[k0 + 12];
    } else {
      av0 = av1 = av2 = av3 = make_float4(0.f, 0.f, 0.f, 0.f);
    }
    float bv[16];
    {
      const float* p = pB + (size_t)k0 * HDIM;
#pragma unroll
      for (int j = 0; j < 16; ++j) bv[j] = p[(size_t)j * HDIM];
    }

    bf16x8 pa0, pa1, pb0, pb1;
    pa0[0] = (__bf16)av0.x; pa0[1] = (__bf16)av0.y; pa0[2] = (__bf16)av0.z; pa0[3] = (__bf16)av0.w;
    pa0[4] = (__bf16)av1.x; pa0[5] = (__bf16)av1.y; pa0[6] = (__bf16)av1.z; pa0[7] = (__bf16)av1.w;
    pa1[0] = (__bf16)av2.x; pa1[1] = (__bf16)av2.y; pa1[2] = (__bf16)av2.z; pa1[3] = (__bf16)av2.w;
    pa1[4] = (__bf16)av3.x; pa1[5] = (__bf16)av3.y; pa1[6] = (__bf16)av3.z; pa1[7] = (__bf16)av3.w;
#pragma unroll
    for (int j = 0; j < 8; ++j) pb0[j] = (__bf16)bv[j];
#pragma unroll
    for (int j = 0; j < 8; ++j) pb1[j] = (__bf16)bv[8 + j];

    *(bf16x8*)&As[arow * ASTRIDE + akh + 0] = pa0;
    *(bf16x8*)&As[arow * ASTRIDE + akh + 8] = pa1;
    *(bf16x8*)&Bs[bcol * ASTRIDE + bkh + 0] = pb0;
    *(bf16x8*)&Bs[bcol * ASTRIDE + bkh + 8] = pb1;
    __syncthreads();

    bf16x8 a[4], b[4];
#pragma unroll
    for (int i = 0; i < 4; ++i)
      a[i] = *(const bf16x8*)&As[(wr + i * 16 + lrow) * ASTRIDE + quad * 8];
#pragma unroll
    for (int j = 0; j < 4; ++j)
      b[j] = *(const bf16x8*)&Bs[(wc + j * 16 + lrow) * ASTRIDE + quad * 8];

#pragma unroll
    for (int i = 0; i < 4; ++i)
#pragma unroll
      for (int j = 0; j < 4; ++j)
        acc[i][j] = __builtin_amdgcn_mfma_f32_16x16x32_bf16(a[i], b[j], acc[i][j], 0, 0, 0);
    __syncthreads();
  }

  const float* be = Eb + (size_t)e * HDIM + col0;
#pragma unroll
  for (int i = 0; i < 4; ++i) {
#pragma unroll
    for (int r = 0; r < 4; ++r) {
      const int row = wr + i * 16 + quad * 4 + r;
      const int tok = toks[row];
      if (tok < 0) continue;
      float* po = Out + (size_t)tok * HDIM + col0;
#pragma unroll
      for (int j = 0; j < 4; ++j) {
        const int col = wc + j * 16 + lrow;
        po[col] = acc[i][j][r] + be[col];
      }
    }
  }
}

// ---------------------------------------------------------------------------
extern "C" void kernel_launch(void* const* d_in, const int* in_sizes, int n_in,
                              void* d_out, int out_size, void* d_ws, size_t ws_size,
                              hipStream_t stream) {
  (void)in_sizes; (void)n_in; (void)out_size; (void)ws_size;

  const float* hs = (const float*)d_in[0];
  const float* w1 = (const float*)d_in[1];
  const float* b1 = (const float*)d_in[2];
  const float* w2 = (const float*)d_in[3];
  const float* b2 = (const float*)d_in[4];
  const float* eW = (const float*)d_in[5];
  const float* eb = (const float*)d_in[6];
  float* out = (float*)d_out;

  // h intermediate lives in d_out (first 33.5 MB): fully consumed before
  // expert_gemm overwrites all of d_out.
  float* h = (float*)d_out;

  char* wsb = (char*)d_ws;
  int* top_idx = (int*)wsb;                        // 65536 B
  int* ctrl    = (int*)(wsb + 65536);              // zeroed block (128 B):
  int* counts  = ctrl;                             //   [0..7]
  int* risky_n = ctrl + 8;                         //   [8]
  int* cursor  = ctrl + 16;                        //   [16..23]
  int* pad_off = (int*)(wsb + 65536 + 128);        // 9 ints
  int* risky   = (int*)(wsb + 65536 + 256);        // RCAP ints, 0xFF
  int* sorted  = risky + RCAP;                     // MAXCHUNK*CHUNK ints, 0xFF

  hipMemsetAsync(ctrl, 0, 128, stream);
  hipMemsetAsync(risky, 0xFF, (RCAP + MAXCHUNK * CHUNK) * sizeof(int), stream);

  gemm1_relu_bf16<<<dim3(MDIM / 128, NTOK / 128), 256, 0, stream>>>(hs, w1, b1, h);
  routing_flag<<<NTOK / 4, 256, 0, stream>>>(h, w2, b2, top_idx, risky_n, risky);
  gemm1_fix<<<dim3(MDIM / 128, RCAP / 128), 256, 0, stream>>>(hs, w1, b1, risky, h);
  rescore_fix<<<RCAP / 32, 256, 0, stream>>>(h, w2, b2, risky, top_idx);
  count_tokens<<<NTOK / 256, 256, 0, stream>>>(top_idx, counts);
  make_offsets<<<1, 64, 0, stream>>>(counts, pad_off);
  scatter_tokens<<<NTOK / 256, 256, 0, stream>>>(top_idx, pad_off, cursor, sorted);
  expert_gemm_bf16<<<dim3(HDIM / 128, MAXCHUNK), 256, 0, stream>>>(hs, eW, eb, sorted, top_idx, out);
}

// Round 4
// 340.584 us; speedup vs baseline: 3.2979x; 1.5595x over previous
//
#include <hip/hip_runtime.h>

// Problem constants (B=4, S=4096 -> 16384 tokens; H=1024; M=H/2=512; E=8)
#define NTOK 16384
#define HDIM 1024
#define MDIM 512
#define NEXP 8
#define CHUNK 128
#define MAXCHUNK 136   // sum_e ceil(c_e/128) <= 135; +1 slack
#define RCAP 4096      // risky-token fixup list capacity (expect ~800)
#define DELTA 0.02f    // top2-gap guard = ~12 sigma of bf16 score noise
#define LSTR 72        // bf16 LDS row stride (conflict-free for all b128 patterns)

typedef __bf16 bf16x8 __attribute__((ext_vector_type(8)));
typedef float floatx4 __attribute__((ext_vector_type(4)));

// ---------------------------------------------------------------------------
// hs fp32 -> bf16 (same layout). 8 elems/thread.
// ---------------------------------------------------------------------------
__global__ __launch_bounds__(256) void cvt_hs(
    const float* __restrict__ src, __bf16* __restrict__ dst)
{
  const size_t i = ((size_t)blockIdx.x * 256 + threadIdx.x) * 8;
  float4 a = *(const float4*)&src[i];
  float4 b = *(const float4*)&src[i + 4];
  bf16x8 o;
  o[0] = (__bf16)a.x; o[1] = (__bf16)a.y; o[2] = (__bf16)a.z; o[3] = (__bf16)a.w;
  o[4] = (__bf16)b.x; o[5] = (__bf16)b.y; o[6] = (__bf16)b.z; o[7] = (__bf16)b.w;
  *(bf16x8*)&dst[i] = o;
}

// ---------------------------------------------------------------------------
// Batched transpose+convert: src fp32 [b][K][C] -> dst bf16 [b][C][K].
// 64x64 tiles via LDS.
// ---------------------------------------------------------------------------
__global__ __launch_bounds__(256) void transpose_cvt(
    const float* __restrict__ src, __bf16* __restrict__ dst, int K, int C)
{
  __shared__ __align__(16) __bf16 T[64 * LSTR];
  const int b = blockIdx.z;
  const int k0 = blockIdx.x * 64, c0 = blockIdx.y * 64;
  const float* S = src + (size_t)b * K * C;
  __bf16* D = dst + (size_t)b * K * C;
  const int t = threadIdx.x;

  {  // load 64 k-rows x 64 cols, write transposed bf16 into LDS
    const int r = t >> 2, cc = (t & 3) * 16;
    const float* p = S + (size_t)(k0 + r) * C + c0 + cc;
    float4 v0 = *(const float4*)&p[0];
    float4 v1 = *(const float4*)&p[4];
    float4 v2 = *(const float4*)&p[8];
    float4 v3 = *(const float4*)&p[12];
    float vv[16] = {v0.x, v0.y, v0.z, v0.w, v1.x, v1.y, v1.z, v1.w,
                    v2.x, v2.y, v2.z, v2.w, v3.x, v3.y, v3.z, v3.w};
#pragma unroll
    for (int j = 0; j < 16; ++j) T[(cc + j) * LSTR + r] = (__bf16)vv[j];
  }
  __syncthreads();
  {  // store: col-major rows, contiguous in k
    const int c = t >> 2, kk = (t & 3) * 16;
    __bf16* q = D + (size_t)(c0 + c) * K + k0 + kk;
    *(float4*)&q[0] = *(const float4*)&T[c * LSTR + kk];
    *(float4*)&q[8] = *(const float4*)&T[c * LSTR + kk + 8];
  }
}

// ---------------------------------------------------------------------------
// GEMM1 (bf16 MFMA, pre-converted inputs): h = relu(hs @ w1 + b1).
// 128x128 tile, BK=64, pure dwordx4 staging, LDS stride 72.
// ---------------------------------------------------------------------------
__global__ __launch_bounds__(256) void gemm1_v2(
    const __bf16* __restrict__ A,   // hs_bf16 [NTOK][HDIM]
    const __bf16* __restrict__ Bt,  // w1t [MDIM][HDIM]
    const float* __restrict__ bias, // b1 [MDIM]
    float* __restrict__ Hout)       // [NTOK][MDIM] fp32
{
  __shared__ __align__(16) __bf16 As[128 * LSTR];
  __shared__ __align__(16) __bf16 Bs[128 * LSTR];

  const int tid = threadIdx.x;
  const int row0 = blockIdx.y * 128, col0 = blockIdx.x * 128;

  const int srow = tid >> 3;        // 0..31
  const int soff = (tid & 7) * 8;   // bf16 units (16B chunks)

  const __bf16* pa = A + (size_t)(row0 + srow) * HDIM + soff;
  const __bf16* pb = Bt + (size_t)(col0 + srow) * HDIM + soff;

  const int wave = tid >> 6, lane = tid & 63;
  const int wr = (wave >> 1) * 64, wc = (wave & 1) * 64;
  const int lrow = lane & 15, quad = lane >> 4;

  floatx4 acc[4][4];
#pragma unroll
  for (int i = 0; i < 4; ++i)
#pragma unroll
    for (int j = 0; j < 4; ++j) acc[i][j] = (floatx4){0.f, 0.f, 0.f, 0.f};

  for (int k0 = 0; k0 < HDIM; k0 += 64) {
#pragma unroll
    for (int p = 0; p < 4; ++p) {
      *(float4*)&As[(srow + p * 32) * LSTR + soff] =
          *(const float4*)&pa[(size_t)(p * 32) * HDIM + k0];
      *(float4*)&Bs[(srow + p * 32) * LSTR + soff] =
          *(const float4*)&pb[(size_t)(p * 32) * HDIM + k0];
    }
    __syncthreads();

#pragma unroll
    for (int kh = 0; kh < 2; ++kh) {
      bf16x8 a[4], b[4];
#pragma unroll
      for (int i = 0; i < 4; ++i)
        a[i] = *(const bf16x8*)&As[(wr + i * 16 + lrow) * LSTR + kh * 32 + quad * 8];
#pragma unroll
      for (int j = 0; j < 4; ++j)
        b[j] = *(const bf16x8*)&Bs[(wc + j * 16 + lrow) * LSTR + kh * 32 + quad * 8];
#pragma unroll
      for (int i = 0; i < 4; ++i)
#pragma unroll
        for (int j = 0; j < 4; ++j)
          acc[i][j] = __builtin_amdgcn_mfma_f32_16x16x32_bf16(a[i], b[j], acc[i][j], 0, 0, 0);
    }
    __syncthreads();
  }

#pragma unroll
  for (int i = 0; i < 4; ++i)
#pragma unroll
    for (int r = 0; r < 4; ++r) {
      const int row = row0 + wr + i * 16 + quad * 4 + r;
#pragma unroll
      for (int j = 0; j < 4; ++j) {
        const int col = col0 + wc + j * 16 + lrow;
        Hout[(size_t)row * MDIM + col] = fmaxf(acc[i][j][r] + bias[col], 0.f);
      }
    }
}

// ---------------------------------------------------------------------------
// Routing: fp32 scores, argmax, delta-guard risky list (unchanged).
// ---------------------------------------------------------------------------
__global__ __launch_bounds__(256) void routing_flag(
    const float* __restrict__ Hq, const float* __restrict__ w2,
    const float* __restrict__ b2, int* __restrict__ top_idx,
    int* __restrict__ risky_n, int* __restrict__ risky)
{
  __shared__ int rbuf[4];
  __shared__ int rcnt;
  if (threadIdx.x == 0) rcnt = 0;
  __syncthreads();

  const int warp = threadIdx.x >> 6;
  const int lane = threadIdx.x & 63;
  const int t = blockIdx.x * 4 + warp;
  const float* hrow = Hq + (size_t)t * MDIM;

  float s[8] = {0, 0, 0, 0, 0, 0, 0, 0};
  for (int k = lane; k < MDIM; k += 64) {
    float hv = hrow[k];
    float4 wa = *(const float4*)&w2[k * 8];
    float4 wb = *(const float4*)&w2[k * 8 + 4];
    s[0] += hv * wa.x; s[1] += hv * wa.y; s[2] += hv * wa.z; s[3] += hv * wa.w;
    s[4] += hv * wb.x; s[5] += hv * wb.y; s[6] += hv * wb.z; s[7] += hv * wb.w;
  }
#pragma unroll
  for (int off = 32; off > 0; off >>= 1)
#pragma unroll
    for (int e = 0; e < 8; ++e) s[e] += __shfl_xor(s[e], off, 64);

  if (lane == 0) {
    float best = s[0] + b2[0], second = -1e30f;
    int bi = 0;
#pragma unroll
    for (int e = 1; e < 8; ++e) {
      float v = s[e] + b2[e];
      if (v > best) { second = best; best = v; bi = e; }
      else if (v > second) second = v;
    }
    top_idx[t] = bi;
    if (best - second < DELTA) {
      int slot = atomicAdd(&rcnt, 1);
      rbuf[slot] = t;
    }
  }
  __syncthreads();
  if (threadIdx.x == 0 && rcnt > 0) {
    int base = atomicAdd(risky_n, rcnt);
    for (int i = 0; i < rcnt; ++i)
      if (base + i < RCAP) risky[base + i] = rbuf[i];
  }
}

// ---------------------------------------------------------------------------
// fp32 fixup, re-shaped for parallelism: 32-token x 64-col tiles
// (grid 8 x RCAP/32 -> ~200 active blocks instead of ~28).
// ---------------------------------------------------------------------------
__global__ __launch_bounds__(256) void gemm1_fix_v2(
    const float* __restrict__ A,    // hs [NTOK][HDIM]
    const float* __restrict__ W,    // w1 [HDIM][MDIM]
    const float* __restrict__ bias, // b1
    const int* __restrict__ risky,  // [RCAP], -1 padded
    float* __restrict__ Hout)       // [NTOK][MDIM]
{
  __shared__ float As[32][33];   // [k][row]
  __shared__ float Bs[32][64];   // [k][col]
  __shared__ int toks[32];

  const int tid = threadIdx.x;
  if (tid < 32) toks[tid] = risky[blockIdx.y * 32 + tid];
  __syncthreads();
  if (toks[0] < 0) return;  // compact list -> uniform empty chunk

  const int col0 = blockIdx.x * 64;
  const int tx = tid & 15, ty = tid >> 4;  // cols tx*4, rows ty & ty+16

  float acc0[4] = {0, 0, 0, 0}, acc1[4] = {0, 0, 0, 0};

  const int sr = tid >> 3;          // 0..31 (A row / B k)
  const int sc4 = (tid & 7) * 4;    // A k chunk
  const int sc8 = (tid & 7) * 8;    // B col chunk
  const int tokS = toks[sr];
  const float* pa = (tokS >= 0) ? A + (size_t)tokS * HDIM + sc4 : A;

  for (int k0 = 0; k0 < HDIM; k0 += 32) {
    float4 av = (tokS >= 0) ? *(const float4*)&pa[k0] : make_float4(0, 0, 0, 0);
    float4 b0 = *(const float4*)&W[(size_t)(k0 + sr) * MDIM + col0 + sc8];
    float4 b1v = *(const float4*)&W[(size_t)(k0 + sr) * MDIM + col0 + sc8 + 4];
    As[sc4 + 0][sr] = av.x; As[sc4 + 1][sr] = av.y;
    As[sc4 + 2][sr] = av.z; As[sc4 + 3][sr] = av.w;
    *(float4*)&Bs[sr][sc8] = b0;
    *(float4*)&Bs[sr][sc8 + 4] = b1v;
    __syncthreads();

#pragma unroll
    for (int k = 0; k < 32; ++k) {
      float a0 = As[k][ty], a1 = As[k][ty + 16];
      float4 bv = *(const float4*)&Bs[k][tx * 4];
      acc0[0] = fmaf(a0, bv.x, acc0[0]); acc0[1] = fmaf(a0, bv.y, acc0[1]);
      acc0[2] = fmaf(a0, bv.z, acc0[2]); acc0[3] = fmaf(a0, bv.w, acc0[3]);
      acc1[0] = fmaf(a1, bv.x, acc1[0]); acc1[1] = fmaf(a1, bv.y, acc1[1]);
      acc1[2] = fmaf(a1, bv.z, acc1[2]); acc1[3] = fmaf(a1, bv.w, acc1[3]);
    }
    __syncthreads();
  }

  const int c = col0 + tx * 4;
  const int t0 = toks[ty], t1 = toks[ty + 16];
  if (t0 >= 0) {
    float4 v;
    v.x = fmaxf(acc0[0] + bias[c + 0], 0.f); v.y = fmaxf(acc0[1] + bias[c + 1], 0.f);
    v.z = fmaxf(acc0[2] + bias[c + 2], 0.f); v.w = fmaxf(acc0[3] + bias[c + 3], 0.f);
    *(float4*)&Hout[(size_t)t0 * MDIM + c] = v;
  }
  if (t1 >= 0) {
    float4 v;
    v.x = fmaxf(acc1[0] + bias[c + 0], 0.f); v.y = fmaxf(acc1[1] + bias[c + 1], 0.f);
    v.z = fmaxf(acc1[2] + bias[c + 2], 0.f); v.w = fmaxf(acc1[3] + bias[c + 3], 0.f);
    *(float4*)&Hout[(size_t)t1 * MDIM + c] = v;
  }
}

// ---------------------------------------------------------------------------
__global__ __launch_bounds__(256) void rescore_fix(
    const float* __restrict__ Hq, const float* __restrict__ w2,
    const float* __restrict__ b2, const int* __restrict__ risky,
    int* __restrict__ top_idx)
{
  const int idx = blockIdx.x * 32 + (threadIdx.x >> 3);
  const int l8 = threadIdx.x & 7;
  const int t = risky[idx];

  float s[8] = {0, 0, 0, 0, 0, 0, 0, 0};
  if (t >= 0) {
    const float* hrow = Hq + (size_t)t * MDIM;
    for (int k = l8; k < MDIM; k += 8) {
      float hv = hrow[k];
      float4 wa = *(const float4*)&w2[k * 8];
      float4 wb = *(const float4*)&w2[k * 8 + 4];
      s[0] += hv * wa.x; s[1] += hv * wa.y; s[2] += hv * wa.z; s[3] += hv * wa.w;
      s[4] += hv * wb.x; s[5] += hv * wb.y; s[6] += hv * wb.z; s[7] += hv * wb.w;
    }
  }
#pragma unroll
  for (int off = 4; off > 0; off >>= 1)
#pragma unroll
    for (int e = 0; e < 8; ++e) s[e] += __shfl_xor(s[e], off, 64);

  if (l8 == 0 && t >= 0) {
    float best = s[0] + b2[0];
    int bi = 0;
#pragma unroll
    for (int e = 1; e < 8; ++e) {
      float v = s[e] + b2[e];
      if (v > best) { best = v; bi = e; }
    }
    top_idx[t] = bi;
  }
}

// ---------------------------------------------------------------------------
__global__ __launch_bounds__(256) void count_tokens(
    const int* __restrict__ top_idx, int* __restrict__ counts)
{
  __shared__ int lc[NEXP];
  if (threadIdx.x < NEXP) lc[threadIdx.x] = 0;
  __syncthreads();
  const int t = blockIdx.x * 256 + threadIdx.x;
  atomicAdd(&lc[top_idx[t]], 1);
  __syncthreads();
  if (threadIdx.x < NEXP) atomicAdd(&counts[threadIdx.x], lc[threadIdx.x]);
}

__global__ void make_offsets(const int* __restrict__ counts,
                             int* __restrict__ pad_off)
{
  if (threadIdx.x == 0) {
    int off = 0;
    for (int e = 0; e < NEXP; ++e) {
      pad_off[e] = off;
      off += ((counts[e] + CHUNK - 1) / CHUNK) * CHUNK;
    }
    pad_off[NEXP] = off;
  }
}

__global__ __launch_bounds__(256) void scatter_tokens(
    const int* __restrict__ top_idx, const int* __restrict__ pad_off,
    int* __restrict__ cursor, int* __restrict__ sorted)
{
  __shared__ int lc[NEXP];
  __shared__ int lbase[NEXP];
  if (threadIdx.x < NEXP) lc[threadIdx.x] = 0;
  __syncthreads();
  const int t = blockIdx.x * 256 + threadIdx.x;
  const int e = top_idx[t];
  const int r = atomicAdd(&lc[e], 1);
  __syncthreads();
  if (threadIdx.x < NEXP)
    lbase[threadIdx.x] = atomicAdd(&cursor[threadIdx.x], lc[threadIdx.x]);
  __syncthreads();
  sorted[pad_off[e] + lbase[e] + r] = t;
}

// ---------------------------------------------------------------------------
// Expert GEMM v2 (bf16 MFMA, pre-converted + pre-transposed W):
// 128x128 tile, BK=64, pure dwordx4 staging.
// ---------------------------------------------------------------------------
__global__ __launch_bounds__(256) void expert_gemm_v2(
    const __bf16* __restrict__ A,   // hs_bf16 [NTOK][HDIM]
    const __bf16* __restrict__ Wt,  // [NEXP][HDIM(col)][HDIM(k)]
    const float* __restrict__ Eb,   // [NEXP][HDIM]
    const int* __restrict__ sorted,
    const int* __restrict__ top_idx,
    float* __restrict__ Out)        // [NTOK][HDIM]
{
  __shared__ __align__(16) __bf16 As[128 * LSTR];
  __shared__ __align__(16) __bf16 Bs[128 * LSTR];
  __shared__ int toks[CHUNK];

  const int tid = threadIdx.x;
  if (tid < CHUNK) toks[tid] = sorted[(size_t)blockIdx.y * CHUNK + tid];
  __syncthreads();
  if (toks[0] < 0) return;

  const int e = top_idx[toks[0]];
  const int col0 = blockIdx.x * 128;

  const int srow = tid >> 3;
  const int soff = (tid & 7) * 8;

  // Per-pass gathered A bases (pad rows read row 0; outputs discarded)
  const __bf16* pa[4];
#pragma unroll
  for (int p = 0; p < 4; ++p) {
    int tk = toks[srow + p * 32];
    pa[p] = A + (size_t)(tk >= 0 ? tk : 0) * HDIM + soff;
  }
  const __bf16* pb = Wt + ((size_t)e * HDIM + col0 + srow) * HDIM + soff;

  const int wave = tid >> 6, lane = tid & 63;
  const int wr = (wave >> 1) * 64, wc = (wave & 1) * 64;
  const int lrow = lane & 15, quad = lane >> 4;

  floatx4 acc[4][4];
#pragma unroll
  for (int i = 0; i < 4; ++i)
#pragma unroll
    for (int j = 0; j < 4; ++j) acc[i][j] = (floatx4){0.f, 0.f, 0.f, 0.f};

  for (int k0 = 0; k0 < HDIM; k0 += 64) {
#pragma unroll
    for (int p = 0; p < 4; ++p) {
      *(float4*)&As[(srow + p * 32) * LSTR + soff] = *(const float4*)&pa[p][k0];
      *(float4*)&Bs[(srow + p * 32) * LSTR + soff] =
          *(const float4*)&pb[(size_t)(p * 32) * HDIM + k0];
    }
    __syncthreads();

#pragma unroll
    for (int kh = 0; kh < 2; ++kh) {
      bf16x8 a[4], b[4];
#pragma unroll
      for (int i = 0; i < 4; ++i)
        a[i] = *(const bf16x8*)&As[(wr + i * 16 + lrow) * LSTR + kh * 32 + quad * 8];
#pragma unroll
      for (int j = 0; j < 4; ++j)
        b[j] = *(const bf16x8*)&Bs[(wc + j * 16 + lrow) * LSTR + kh * 32 + quad * 8];
#pragma unroll
      for (int i = 0; i < 4; ++i)
#pragma unroll
        for (int j = 0; j < 4; ++j)
          acc[i][j] = __builtin_amdgcn_mfma_f32_16x16x32_bf16(a[i], b[j], acc[i][j], 0, 0, 0);
    }
    __syncthreads();
  }

  const float* be = Eb + (size_t)e * HDIM + col0;
#pragma unroll
  for (int i = 0; i < 4; ++i)
#pragma unroll
    for (int r = 0; r < 4; ++r) {
      const int row = wr + i * 16 + quad * 4 + r;
      const int tok = toks[row];
      if (tok < 0) continue;
      float* po = Out + (size_t)tok * HDIM + col0;
#pragma unroll
      for (int j = 0; j < 4; ++j) {
        const int col = wc + j * 16 + lrow;
        po[col] = acc[i][j][r] + be[col];
      }
    }
}

// ---------------------------------------------------------------------------
extern "C" void kernel_launch(void* const* d_in, const int* in_sizes, int n_in,
                              void* d_out, int out_size, void* d_ws, size_t ws_size,
                              hipStream_t stream) {
  (void)in_sizes; (void)n_in; (void)out_size; (void)ws_size;

  const float* hs = (const float*)d_in[0];
  const float* w1 = (const float*)d_in[1];
  const float* b1 = (const float*)d_in[2];
  const float* w2 = (const float*)d_in[3];
  const float* b2 = (const float*)d_in[4];
  const float* eW = (const float*)d_in[5];
  const float* eb = (const float*)d_in[6];
  float* out = (float*)d_out;

  // h fp32 intermediate lives in d_out (first 33.5 MB): fully consumed before
  // expert_gemm_v2 overwrites all of d_out.
  float* h = (float*)d_out;

  char* wsb = (char*)d_ws;
  int* top_idx = (int*)wsb;                         // 65536 B
  int* ctrl    = (int*)(wsb + 65536);               // zeroed 128 B:
  int* counts  = ctrl;                              //   [0..7]
  int* risky_n = ctrl + 8;                          //   [8]
  int* cursor  = ctrl + 16;                         //   [16..23]
  int* pad_off = (int*)(wsb + 65536 + 128);         // 9 ints
  int* risky   = (int*)(wsb + 65792);               // RCAP ints, 0xFF
  int* sorted  = risky + RCAP;                      // MAXCHUNK*CHUNK ints, 0xFF
  __bf16* hs_bf = (__bf16*)(wsb + 163840);          // 33,554,432 B
  __bf16* w1t   = (__bf16*)(wsb + 163840 + 33554432);            // 1,048,576 B
  __bf16* eWt   = (__bf16*)(wsb + 163840 + 33554432 + 1048576);  // 16,777,216 B
  // total ws usage ~51.5 MB

  hipMemsetAsync(ctrl, 0, 128, stream);
  hipMemsetAsync(risky, 0xFF, (RCAP + MAXCHUNK * CHUNK) * sizeof(int), stream);

  cvt_hs<<<NTOK * HDIM / (256 * 8), 256, 0, stream>>>(hs, hs_bf);
  transpose_cvt<<<dim3(HDIM / 64, MDIM / 64, 1), 256, 0, stream>>>(w1, w1t, HDIM, MDIM);
  transpose_cvt<<<dim3(HDIM / 64, HDIM / 64, NEXP), 256, 0, stream>>>(eW, eWt, HDIM, HDIM);

  gemm1_v2<<<dim3(MDIM / 128, NTOK / 128), 256, 0, stream>>>(hs_bf, w1t, b1, h);
  routing_flag<<<NTOK / 4, 256, 0, stream>>>(h, w2, b2, top_idx, risky_n, risky);
  gemm1_fix_v2<<<dim3(MDIM / 64, RCAP / 32), 256, 0, stream>>>(hs, w1, b1, risky, h);
  rescore_fix<<<RCAP / 32, 256, 0, stream>>>(h, w2, b2, risky, top_idx);
  count_tokens<<<NTOK / 256, 256, 0, stream>>>(top_idx, counts);
  make_offsets<<<1, 64, 0, stream>>>(counts, pad_off);
  scatter_tokens<<<NTOK / 256, 256, 0, stream>>>(top_idx, pad_off, cursor, sorted);
  expert_gemm_v2<<<dim3(HDIM / 128, MAXCHUNK), 256, 0, stream>>>(hs_bf, eWt, eb, sorted, top_idx, out);
}

// Round 5
// 331.666 us; speedup vs baseline: 3.3865x; 1.0269x over previous
//
#include <hip/hip_runtime.h>

// Problem constants (B=4, S=4096 -> 16384 tokens; H=1024; M=H/2=512; E=8)
#define NTOK 16384
#define HDIM 1024
#define MDIM 512
#define NEXP 8
#define CHUNK 128
#define MAXCHUNK 136   // sum_e ceil(c_e/128) <= 135; +1 slack
#define RCAP 4096      // risky-token fixup list capacity (expect ~800)
#define DELTA 0.02f    // top2-gap guard >> bf16 score noise (~1e-3)
#define LSTR 72        // fp32->bf16 transpose LDS stride

typedef __bf16 bf16x8 __attribute__((ext_vector_type(8)));
typedef float floatx4 __attribute__((ext_vector_type(4)));

// Async global->LDS 16B: LDS dest is wave-uniform base + lane*16 (HW-fixed).
__device__ __forceinline__ void gll16(const void* g, void* l) {
  __builtin_amdgcn_global_load_lds(
      (const __attribute__((address_space(1))) void*)g,
      (__attribute__((address_space(3))) void*)l, 16, 0, 0);
}

// ---------------------------------------------------------------------------
// hs fp32 -> bf16 (same layout).
// ---------------------------------------------------------------------------
__global__ __launch_bounds__(256) void cvt_hs(
    const float* __restrict__ src, __bf16* __restrict__ dst)
{
  const size_t i = ((size_t)blockIdx.x * 256 + threadIdx.x) * 8;
  float4 a = *(const float4*)&src[i];
  float4 b = *(const float4*)&src[i + 4];
  bf16x8 o;
  o[0] = (__bf16)a.x; o[1] = (__bf16)a.y; o[2] = (__bf16)a.z; o[3] = (__bf16)a.w;
  o[4] = (__bf16)b.x; o[5] = (__bf16)b.y; o[6] = (__bf16)b.z; o[7] = (__bf16)b.w;
  *(bf16x8*)&dst[i] = o;
}

// ---------------------------------------------------------------------------
// Batched transpose+convert: src fp32 [b][K][C] -> dst bf16 [b][C][K].
// ---------------------------------------------------------------------------
__global__ __launch_bounds__(256) void transpose_cvt(
    const float* __restrict__ src, __bf16* __restrict__ dst, int K, int C)
{
  __shared__ __align__(16) __bf16 T[64 * LSTR];
  const int b = blockIdx.z;
  const int k0 = blockIdx.x * 64, c0 = blockIdx.y * 64;
  const float* S = src + (size_t)b * K * C;
  __bf16* D = dst + (size_t)b * K * C;
  const int t = threadIdx.x;
  {
    const int r = t >> 2, cc = (t & 3) * 16;
    const float* p = S + (size_t)(k0 + r) * C + c0 + cc;
    float4 v0 = *(const float4*)&p[0];
    float4 v1 = *(const float4*)&p[4];
    float4 v2 = *(const float4*)&p[8];
    float4 v3 = *(const float4*)&p[12];
    float vv[16] = {v0.x, v0.y, v0.z, v0.w, v1.x, v1.y, v1.z, v1.w,
                    v2.x, v2.y, v2.z, v2.w, v3.x, v3.y, v3.z, v3.w};
#pragma unroll
    for (int j = 0; j < 16; ++j) T[(cc + j) * LSTR + r] = (__bf16)vv[j];
  }
  __syncthreads();
  {
    const int c = t >> 2, kk = (t & 3) * 16;
    __bf16* q = D + (size_t)(c0 + c) * K + k0 + kk;
    *(float4*)&q[0] = *(const float4*)&T[c * LSTR + kk];
    *(float4*)&q[8] = *(const float4*)&T[c * LSTR + kk + 8];
  }
}

// ---------------------------------------------------------------------------
// GEMM1 + fused routing-score partials. 128x128 tile, BK=64,
// global_load_lds staging with XOR-swizzled k-chunks (conflict-free, no pad).
// Epilogue computes s_part[colblk][t][e] = sum_cols relu(h)*w2 — no h output.
// ---------------------------------------------------------------------------
__global__ __launch_bounds__(256) void gemm1_score(
    const __bf16* __restrict__ A,    // hs_bf16 [NTOK][HDIM]
    const __bf16* __restrict__ Bt,   // w1t [MDIM][HDIM]
    const float* __restrict__ bias,  // b1 [MDIM]
    const float* __restrict__ w2,    // [MDIM][8]
    float* __restrict__ scores_part) // [4][NTOK][8]
{
  __shared__ __align__(16) __bf16 As[128 * 64];
  __shared__ __align__(16) __bf16 Bs[128 * 64];

  const int tid = threadIdx.x;
  const int row0 = blockIdx.y * 128, col0 = blockIdx.x * 128;
  const int wave = tid >> 6, lane = tid & 63;
  const int lrow8 = lane >> 3;
  const int gchunk = (lane & 7) ^ lrow8;   // global-side swizzle
  const int wr = (wave >> 1) * 64, wc = (wave & 1) * 64;
  const int lrow = lane & 15, quad = lane >> 4;

  const __bf16 *pa[4], *pb[4];
#pragma unroll
  for (int p = 0; p < 4; ++p) {
    const int rb = wave * 8 + p * 32;   // 8-aligned -> row&7 == lrow8
    pa[p] = A + (size_t)(row0 + rb + lrow8) * HDIM + gchunk * 8;
    pb[p] = Bt + (size_t)(col0 + rb + lrow8) * HDIM + gchunk * 8;
  }

  floatx4 acc[4][4];
#pragma unroll
  for (int i = 0; i < 4; ++i)
#pragma unroll
    for (int j = 0; j < 4; ++j) acc[i][j] = (floatx4){0.f, 0.f, 0.f, 0.f};

  for (int k0 = 0; k0 < HDIM; k0 += 64) {
#pragma unroll
    for (int p = 0; p < 4; ++p) {
      const int rb = wave * 8 + p * 32;
      gll16(pa[p] + k0, &As[rb * 64]);
      gll16(pb[p] + k0, &Bs[rb * 64]);
    }
    __syncthreads();
#pragma unroll
    for (int kh = 0; kh < 2; ++kh) {
      bf16x8 a[4], b[4];
#pragma unroll
      for (int i = 0; i < 4; ++i)
        a[i] = *(const bf16x8*)&As[(wr + i * 16 + lrow) * 64 +
                                   (((kh * 4 + quad) ^ (lrow & 7)) * 8)];
#pragma unroll
      for (int j = 0; j < 4; ++j)
        b[j] = *(const bf16x8*)&Bs[(wc + j * 16 + lrow) * 64 +
                                   (((kh * 4 + quad) ^ (lrow & 7)) * 8)];
#pragma unroll
      for (int i = 0; i < 4; ++i)
#pragma unroll
        for (int j = 0; j < 4; ++j)
          acc[i][j] = __builtin_amdgcn_mfma_f32_16x16x32_bf16(a[i], b[j], acc[i][j], 0, 0, 0);
    }
    __syncthreads();
  }

  // ---- fused scoring epilogue (reuses As/Bs LDS) ----
  float* w2s = (float*)As;    // 4KB: w2 cols col0..col0+127
  float* sblk = (float*)Bs;   // 8KB: [2 wc-halves][128 rows][8]
  *(float4*)&w2s[tid * 4] = *(const float4*)&w2[col0 * 8 + tid * 4];
  __syncthreads();

  float bj[4];
  float4 wja[4], wjb[4];
#pragma unroll
  for (int j = 0; j < 4; ++j) {
    const int cl = wc + j * 16 + lrow;
    bj[j] = bias[col0 + cl];
    wja[j] = *(const float4*)&w2s[cl * 8];
    wjb[j] = *(const float4*)&w2s[cl * 8 + 4];
  }

#pragma unroll
  for (int i = 0; i < 4; ++i) {
#pragma unroll
    for (int r = 0; r < 4; ++r) {
      float4 sA = {0, 0, 0, 0}, sB = {0, 0, 0, 0};
#pragma unroll
      for (int j = 0; j < 4; ++j) {
        float h = fmaxf(acc[i][j][r] + bj[j], 0.f);
        sA.x += h * wja[j].x; sA.y += h * wja[j].y;
        sA.z += h * wja[j].z; sA.w += h * wja[j].w;
        sB.x += h * wjb[j].x; sB.y += h * wjb[j].y;
        sB.z += h * wjb[j].z; sB.w += h * wjb[j].w;
      }
#pragma unroll
      for (int m = 1; m <= 8; m <<= 1) {
        sA.x += __shfl_xor(sA.x, m, 64); sA.y += __shfl_xor(sA.y, m, 64);
        sA.z += __shfl_xor(sA.z, m, 64); sA.w += __shfl_xor(sA.w, m, 64);
        sB.x += __shfl_xor(sB.x, m, 64); sB.y += __shfl_xor(sB.y, m, 64);
        sB.z += __shfl_xor(sB.z, m, 64); sB.w += __shfl_xor(sB.w, m, 64);
      }
      if (lrow == 0) {
        const int rloc = wr + i * 16 + quad * 4 + r;  // unique writer per slot
        *(float4*)&sblk[((wave & 1) * 128 + rloc) * 8] = sA;
        *(float4*)&sblk[((wave & 1) * 128 + rloc) * 8 + 4] = sB;
      }
    }
  }
  __syncthreads();
  {
    const int r = tid >> 1, e4 = (tid & 1) * 4;
    float4 v0 = *(const float4*)&sblk[r * 8 + e4];
    float4 v1 = *(const float4*)&sblk[(128 + r) * 8 + e4];
    float4 o = {v0.x + v1.x, v0.y + v1.y, v0.z + v1.z, v0.w + v1.w};
    *(float4*)&scores_part[((size_t)blockIdx.x * NTOK + row0 + r) * 8 + e4] = o;
  }
}

// ---------------------------------------------------------------------------
// Sum 4 col-block partials, +b2, argmax; flag near-ties (gap < DELTA).
// ---------------------------------------------------------------------------
__global__ __launch_bounds__(256) void routing_argmax(
    const float* __restrict__ scores_part, const float* __restrict__ b2,
    int* __restrict__ top_idx, int* __restrict__ risky_n,
    int* __restrict__ risky)
{
  __shared__ int rbuf[256];
  __shared__ int rcnt, rbase;
  if (threadIdx.x == 0) rcnt = 0;
  __syncthreads();

  const int t = blockIdx.x * 256 + threadIdx.x;
  float4 sa = {0, 0, 0, 0}, sb = {0, 0, 0, 0};
#pragma unroll
  for (int c = 0; c < 4; ++c) {
    float4 va = *(const float4*)&scores_part[((size_t)c * NTOK + t) * 8];
    float4 vb = *(const float4*)&scores_part[((size_t)c * NTOK + t) * 8 + 4];
    sa.x += va.x; sa.y += va.y; sa.z += va.z; sa.w += va.w;
    sb.x += vb.x; sb.y += vb.y; sb.z += vb.z; sb.w += vb.w;
  }
  float s[8] = {sa.x + b2[0], sa.y + b2[1], sa.z + b2[2], sa.w + b2[3],
                sb.x + b2[4], sb.y + b2[5], sb.z + b2[6], sb.w + b2[7]};
  float best = s[0], second = -1e30f;
  int bi = 0;
#pragma unroll
  for (int e = 1; e < 8; ++e) {
    if (s[e] > best) { second = best; best = s[e]; bi = e; }
    else if (s[e] > second) second = s[e];
  }
  top_idx[t] = bi;
  if (best - second < DELTA) rbuf[atomicAdd(&rcnt, 1)] = t;
  __syncthreads();
  if (threadIdx.x == 0 && rcnt > 0) rbase = atomicAdd(risky_n, rcnt);
  __syncthreads();
  if ((int)threadIdx.x < rcnt) {
    int slot = rbase + threadIdx.x;
    if (slot < RCAP) risky[slot] = rbuf[threadIdx.x];
  }
}

// ---------------------------------------------------------------------------
// Exact fp32 h for risky tokens -> compact hfix[RCAP][MDIM].
// 32-token x 64-col tiles for parallelism.
// ---------------------------------------------------------------------------
__global__ __launch_bounds__(256) void gemm1_fix_v2(
    const float* __restrict__ A, const float* __restrict__ W,
    const float* __restrict__ bias, const int* __restrict__ risky,
    float* __restrict__ hfix)
{
  __shared__ float As[32][33];
  __shared__ float Bs[32][64];
  __shared__ int toks[32];

  const int tid = threadIdx.x;
  if (tid < 32) toks[tid] = risky[blockIdx.y * 32 + tid];
  __syncthreads();
  if (toks[0] < 0) return;

  const int col0 = blockIdx.x * 64;
  const int tx = tid & 15, ty = tid >> 4;
  float acc0[4] = {0, 0, 0, 0}, acc1[4] = {0, 0, 0, 0};

  const int sr = tid >> 3;
  const int sc4 = (tid & 3) * 8;         // A k chunk base (two float4)
  const int lo = tid & 7;
  const int sc8 = lo * 8;                // B col chunk
  const int tokS = toks[sr];
  const float* pa = (tokS >= 0) ? A + (size_t)tokS * HDIM : A;

  for (int k0 = 0; k0 < HDIM; k0 += 32) {
    float4 av = make_float4(0, 0, 0, 0);
    if (tokS >= 0) av = *(const float4*)&pa[k0 + (lo & 3) * 4 + (lo >> 2) * 16];
    float4 b0 = *(const float4*)&W[(size_t)(k0 + sr) * MDIM + col0 + sc8];
    float4 b1v = *(const float4*)&W[(size_t)(k0 + sr) * MDIM + col0 + sc8 + 4];
    const int kk = (lo & 3) * 4 + (lo >> 2) * 16;
    As[kk + 0][sr] = av.x; As[kk + 1][sr] = av.y;
    As[kk + 2][sr] = av.z; As[kk + 3][sr] = av.w;
    (void)sc4;
    *(float4*)&Bs[sr][sc8] = b0;
    *(float4*)&Bs[sr][sc8 + 4] = b1v;
    __syncthreads();

#pragma unroll
    for (int k = 0; k < 32; ++k) {
      float a0 = As[k][ty], a1 = As[k][ty + 16];
      float4 bv = *(const float4*)&Bs[k][tx * 4];
      acc0[0] = fmaf(a0, bv.x, acc0[0]); acc0[1] = fmaf(a0, bv.y, acc0[1]);
      acc0[2] = fmaf(a0, bv.z, acc0[2]); acc0[3] = fmaf(a0, bv.w, acc0[3]);
      acc1[0] = fmaf(a1, bv.x, acc1[0]); acc1[1] = fmaf(a1, bv.y, acc1[1]);
      acc1[2] = fmaf(a1, bv.z, acc1[2]); acc1[3] = fmaf(a1, bv.w, acc1[3]);
    }
    __syncthreads();
  }

  const int c = col0 + tx * 4;
  const int i0 = blockIdx.y * 32 + ty, i1 = blockIdx.y * 32 + ty + 16;
  if (toks[ty] >= 0) {
    float4 v;
    v.x = fmaxf(acc0[0] + bias[c + 0], 0.f); v.y = fmaxf(acc0[1] + bias[c + 1], 0.f);
    v.z = fmaxf(acc0[2] + bias[c + 2], 0.f); v.w = fmaxf(acc0[3] + bias[c + 3], 0.f);
    *(float4*)&hfix[(size_t)i0 * MDIM + c] = v;
  }
  if (toks[ty + 16] >= 0) {
    float4 v;
    v.x = fmaxf(acc1[0] + bias[c + 0], 0.f); v.y = fmaxf(acc1[1] + bias[c + 1], 0.f);
    v.z = fmaxf(acc1[2] + bias[c + 2], 0.f); v.w = fmaxf(acc1[3] + bias[c + 3], 0.f);
    *(float4*)&hfix[(size_t)i1 * MDIM + c] = v;
  }
}

// ---------------------------------------------------------------------------
// Exact rescore of risky tokens from hfix; overwrite top_idx.
// ---------------------------------------------------------------------------
__global__ __launch_bounds__(256) void rescore_fix(
    const float* __restrict__ hfix, const float* __restrict__ w2,
    const float* __restrict__ b2, const int* __restrict__ risky,
    int* __restrict__ top_idx)
{
  const int idx = blockIdx.x * 32 + (threadIdx.x >> 3);
  const int l8 = threadIdx.x & 7;
  const int t = risky[idx];

  float s[8] = {0, 0, 0, 0, 0, 0, 0, 0};
  if (t >= 0) {
    const float* hrow = hfix + (size_t)idx * MDIM;
    for (int k = l8; k < MDIM; k += 8) {
      float hv = hrow[k];
      float4 wa = *(const float4*)&w2[k * 8];
      float4 wb = *(const float4*)&w2[k * 8 + 4];
      s[0] += hv * wa.x; s[1] += hv * wa.y; s[2] += hv * wa.z; s[3] += hv * wa.w;
      s[4] += hv * wb.x; s[5] += hv * wb.y; s[6] += hv * wb.z; s[7] += hv * wb.w;
    }
  }
#pragma unroll
  for (int off = 4; off > 0; off >>= 1)
#pragma unroll
    for (int e = 0; e < 8; ++e) s[e] += __shfl_xor(s[e], off, 64);

  if (l8 == 0 && t >= 0) {
    float best = s[0] + b2[0];
    int bi = 0;
#pragma unroll
    for (int e = 1; e < 8; ++e) {
      float v = s[e] + b2[e];
      if (v > best) { best = v; bi = e; }
    }
    top_idx[t] = bi;
  }
}

// ---------------------------------------------------------------------------
__global__ __launch_bounds__(256) void count_tokens(
    const int* __restrict__ top_idx, int* __restrict__ counts)
{
  __shared__ int lc[NEXP];
  if (threadIdx.x < NEXP) lc[threadIdx.x] = 0;
  __syncthreads();
  atomicAdd(&lc[top_idx[blockIdx.x * 256 + threadIdx.x]], 1);
  __syncthreads();
  if (threadIdx.x < NEXP) atomicAdd(&counts[threadIdx.x], lc[threadIdx.x]);
}

// Scatter with inline padded-offset prefix (counts finalized previous kernel).
__global__ __launch_bounds__(256) void scatter_tokens(
    const int* __restrict__ top_idx, const int* __restrict__ counts,
    int* __restrict__ cursor, int* __restrict__ sorted)
{
  __shared__ int lc[NEXP], lbase[NEXP], off_s[NEXP];
  if (threadIdx.x < NEXP) lc[threadIdx.x] = 0;
  if (threadIdx.x == 0) {
    int off = 0;
    for (int e = 0; e < NEXP; ++e) {
      off_s[e] = off;
      off += ((counts[e] + CHUNK - 1) / CHUNK) * CHUNK;
    }
  }
  __syncthreads();
  const int t = blockIdx.x * 256 + threadIdx.x;
  const int e = top_idx[t];
  const int r = atomicAdd(&lc[e], 1);
  __syncthreads();
  if (threadIdx.x < NEXP)
    lbase[threadIdx.x] = atomicAdd(&cursor[threadIdx.x], lc[threadIdx.x]);
  __syncthreads();
  sorted[off_s[e] + lbase[e] + r] = t;
}

// ---------------------------------------------------------------------------
// Expert GEMM v3: 128x128 tile, BK=64, swizzled global_load_lds staging.
// ---------------------------------------------------------------------------
__global__ __launch_bounds__(256) void expert_gemm_v3(
    const __bf16* __restrict__ A,   // hs_bf16 [NTOK][HDIM]
    const __bf16* __restrict__ Wt,  // [NEXP][HDIM(col)][HDIM(k)]
    const float* __restrict__ Eb,   // [NEXP][HDIM]
    const int* __restrict__ sorted,
    const int* __restrict__ top_idx,
    float* __restrict__ Out)
{
  __shared__ __align__(16) __bf16 As[128 * 64];
  __shared__ __align__(16) __bf16 Bs[128 * 64];
  __shared__ int toks[CHUNK];

  const int tid = threadIdx.x;
  if (tid < CHUNK) toks[tid] = sorted[(size_t)blockIdx.y * CHUNK + tid];
  __syncthreads();
  if (toks[0] < 0) return;

  const int e = top_idx[toks[0]];
  const int col0 = blockIdx.x * 128;
  const int wave = tid >> 6, lane = tid & 63;
  const int lrow8 = lane >> 3;
  const int gchunk = (lane & 7) ^ lrow8;
  const int wr = (wave >> 1) * 64, wc = (wave & 1) * 64;
  const int lrow = lane & 15, quad = lane >> 4;

  const __bf16 *pa[4], *pb[4];
#pragma unroll
  for (int p = 0; p < 4; ++p) {
    const int rb = wave * 8 + p * 32;
    const int tk = toks[rb + lrow8];
    pa[p] = A + (size_t)(tk < 0 ? 0 : tk) * HDIM + gchunk * 8;
    pb[p] = Wt + ((size_t)e * HDIM + col0 + rb + lrow8) * HDIM + gchunk * 8;
  }

  floatx4 acc[4][4];
#pragma unroll
  for (int i = 0; i < 4; ++i)
#pragma unroll
    for (int j = 0; j < 4; ++j) acc[i][j] = (floatx4){0.f, 0.f, 0.f, 0.f};

  for (int k0 = 0; k0 < HDIM; k0 += 64) {
#pragma unroll
    for (int p = 0; p < 4; ++p) {
      const int rb = wave * 8 + p * 32;
      gll16(pa[p] + k0, &As[rb * 64]);
      gll16(pb[p] + k0, &Bs[rb * 64]);
    }
    __syncthreads();
#pragma unroll
    for (int kh = 0; kh < 2; ++kh) {
      bf16x8 a[4], b[4];
#pragma unroll
      for (int i = 0; i < 4; ++i)
        a[i] = *(const bf16x8*)&As[(wr + i * 16 + lrow) * 64 +
                                   (((kh * 4 + quad) ^ (lrow & 7)) * 8)];
#pragma unroll
      for (int j = 0; j < 4; ++j)
        b[j] = *(const bf16x8*)&Bs[(wc + j * 16 + lrow) * 64 +
                                   (((kh * 4 + quad) ^ (lrow & 7)) * 8)];
#pragma unroll
      for (int i = 0; i < 4; ++i)
#pragma unroll
        for (int j = 0; j < 4; ++j)
          acc[i][j] = __builtin_amdgcn_mfma_f32_16x16x32_bf16(a[i], b[j], acc[i][j], 0, 0, 0);
    }
    __syncthreads();
  }

  const float* be = Eb + (size_t)e * HDIM + col0;
#pragma unroll
  for (int i = 0; i < 4; ++i)
#pragma unroll
    for (int r = 0; r < 4; ++r) {
      const int row = wr + i * 16 + quad * 4 + r;
      const int tok = toks[row];
      if (tok < 0) continue;
      float* po = Out + (size_t)tok * HDIM + col0;
#pragma unroll
      for (int j = 0; j < 4; ++j) {
        const int col = wc + j * 16 + lrow;
        po[col] = acc[i][j][r] + be[col];
      }
    }
}

// ---------------------------------------------------------------------------
extern "C" void kernel_launch(void* const* d_in, const int* in_sizes, int n_in,
                              void* d_out, int out_size, void* d_ws, size_t ws_size,
                              hipStream_t stream) {
  (void)in_sizes; (void)n_in; (void)out_size; (void)ws_size;

  const float* hs = (const float*)d_in[0];
  const float* w1 = (const float*)d_in[1];
  const float* b1 = (const float*)d_in[2];
  const float* w2 = (const float*)d_in[3];
  const float* b2 = (const float*)d_in[4];
  const float* eW = (const float*)d_in[5];
  const float* eb = (const float*)d_in[6];
  float* out = (float*)d_out;

  // d_out doubles as scratch until expert_gemm_v3 (the last kernel)
  // overwrites it completely: hfix [RCAP][MDIM] + scores_part [4][NTOK][8].
  float* hfix = (float*)d_out;                       // 8 MB
  float* scores_part = hfix + (size_t)RCAP * MDIM;   // 2 MB

  char* wsb = (char*)d_ws;
  int* top_idx = (int*)wsb;                          // 65536 B
  int* ctrl    = (int*)(wsb + 65536);                // zeroed 128 B:
  int* counts  = ctrl;                               //   [0..7]
  int* risky_n = ctrl + 8;                           //   [8]
  int* cursor  = ctrl + 16;                          //   [16..23]
  int* risky   = (int*)(wsb + 65792);                // RCAP ints, 0xFF
  int* sorted  = risky + RCAP;                       // MAXCHUNK*CHUNK, 0xFF
  __bf16* hs_bf = (__bf16*)(wsb + 163840);           // 33.5 MB
  __bf16* w1t   = (__bf16*)(wsb + 163840 + 33554432);
  __bf16* eWt   = (__bf16*)(wsb + 163840 + 33554432 + 1048576);

  hipMemsetAsync(ctrl, 0, 128, stream);
  hipMemsetAsync(risky, 0xFF, (RCAP + MAXCHUNK * CHUNK) * sizeof(int), stream);

  cvt_hs<<<NTOK * HDIM / (256 * 8), 256, 0, stream>>>(hs, hs_bf);
  transpose_cvt<<<dim3(HDIM / 64, MDIM / 64, 1), 256, 0, stream>>>(w1, w1t, HDIM, MDIM);
  transpose_cvt<<<dim3(HDIM / 64, HDIM / 64, NEXP), 256, 0, stream>>>(eW, eWt, HDIM, HDIM);

  gemm1_score<<<dim3(MDIM / 128, NTOK / 128), 256, 0, stream>>>(hs_bf, w1t, b1, w2, scores_part);
  routing_argmax<<<NTOK / 256, 256, 0, stream>>>(scores_part, b2, top_idx, risky_n, risky);
  gemm1_fix_v2<<<dim3(MDIM / 64, RCAP / 32), 256, 0, stream>>>(hs, w1, b1, risky, hfix);
  rescore_fix<<<RCAP / 32, 256, 0, stream>>>(hfix, w2, b2, risky, top_idx);
  count_tokens<<<NTOK / 256, 256, 0, stream>>>(top_idx, counts);
  scatter_tokens<<<NTOK / 256, 256, 0, stream>>>(top_idx, counts, cursor, sorted);
  expert_gemm_v3<<<dim3(HDIM / 128, MAXCHUNK), 256, 0, stream>>>(hs_bf, eWt, eb, sorted, top_idx, out);
}